// Round 4
// baseline (280.232 us; speedup 1.0000x reference)
//
#include <hip/hip_runtime.h>

#define H_  16
#define L_  1024
#define D_  1024
#define DH  64

typedef short bf16x8 __attribute__((ext_vector_type(8)));
typedef float f32x4  __attribute__((ext_vector_type(4)));

__device__ __forceinline__ ushort f2bf(float f) {
  union { float f; unsigned int u; } x; x.f = f;
  unsigned int u = x.u;
  u = (u + 0x7fffu + ((u >> 16) & 1u)) >> 16;   // RNE
  return (ushort)u;
}
__device__ __forceinline__ float bf2f(ushort s) {
  union { unsigned int u; float f; } x; x.u = ((unsigned int)s) << 16;
  return x.f;
}

// Software packed f32->bf16 (round-half-up) -> [bf16(b)<<16 | bf16(a)].
__device__ __forceinline__ unsigned int pkbf(float a, float b) {
  union { float f; unsigned int u; } xa, xb; xa.f = a; xb.f = b;
  unsigned int ua = xa.u + 0x8000u;
  unsigned int ub = xb.u + 0x8000u;
  return (ua >> 16) | (ub & 0xffff0000u);
}
__device__ __forceinline__ ushort lo16(unsigned int v) { return (ushort)v; }
__device__ __forceinline__ ushort hi16(unsigned int v) { return (ushort)(v >> 16); }

// QEr-region swizzle (ushort index): XOR bits[5:4] with bits[13:12].
// Bijection; applied to ALL QEr-epoch accesses (stores, zeros, skew reads).
// Skew-read F = rr*1024 + c has (F>>12)&3 == qd(+uniform carry) -> spreads the
// 4 qd groups across all 32 banks (was 8-way conflict on 8 banks).
__device__ __forceinline__ int SZ(int F) { return F ^ (((F >> 12) & 3) << 4); }

// Fragment-interleaved (AF) layout for an M x 1024 bf16 matrix:
// chunk (mb=m>>7, kb=k>>5, am=(m>>4)&7) of 512 ushort; within: lane=((k>>3)&3)*16+(m&15), jj=k&7.
__device__ __forceinline__ size_t afi(int m, int k) {
  return (((size_t)((m >> 7) * 32 + (k >> 5)) * 8 + ((m >> 4) & 7)) << 9)
       + ((size_t)((((k >> 3) & 3) << 4) + (m & 15)) << 3) + (k & 7);
}

// async global->LDS 16B per lane: dst = (wave-uniform) l + lane*16, src = per-lane g.
__device__ __forceinline__ void gl_lds16(const ushort* g, ushort* l) {
  __builtin_amdgcn_global_load_lds(
      (const __attribute__((address_space(1))) void*)g,
      (__attribute__((address_space(3))) void*)l, 16, 0, 0);
}

// q/k/v fp32 row-major -> bf16 AF layout.
__global__ __launch_bounds__(256) void cvt3_kernel(
    const float* __restrict__ q, const float* __restrict__ k, const float* __restrict__ v,
    ushort* __restrict__ qb, ushort* __restrict__ kb, ushort* __restrict__ vb) {
  const int z = blockIdx.y;
  const float* in = (z == 0) ? q : (z == 1) ? k : v;
  ushort* out = (z == 0) ? qb : (z == 1) ? kb : vb;
  int idx = (blockIdx.x * 256 + threadIdx.x) * 8;
  int m = idx >> 10, kk = idx & 1023;
  float4 f0 = *(const float4*)(in + idx);
  float4 f1 = *(const float4*)(in + idx + 4);
  uint4 o;
  o.x = pkbf(f0.x, f0.y); o.y = pkbf(f0.z, f0.w);
  o.z = pkbf(f1.x, f1.y); o.w = pkbf(f1.z, f1.w);
  *(uint4*)(out + afi(m, kk)) = o;
}

// Er fp32 [1024][64] -> ErF fragment-interleaved bf16 (attn-style fragments).
__global__ __launch_bounds__(256) void erF_kernel(const float* __restrict__ Er,
                                                  ushort* __restrict__ ErF) {
  int t = blockIdx.x * 256 + threadIdx.x;   // [0, 8192)
  int lane = t & 63, ph = (t >> 6) & 1, jg = t >> 7;
  int m = jg * 16 + (lane & 15);
  int k = ph * 32 + (lane >> 4) * 8;
  float4 f0 = *(const float4*)(Er + m * 64 + k);
  float4 f1 = *(const float4*)(Er + m * 64 + k + 4);
  uint4 o;
  o.x = pkbf(f0.x, f0.y); o.y = pkbf(f0.z, f0.w);
  o.z = pkbf(f1.x, f1.y); o.w = pkbf(f1.z, f1.w);
  *(uint4*)(ErF + t * 8) = o;
}

// 4 weight transposes fused: W fp32 [k][n] -> WT bf16 AF layout of BT[n][k].
__global__ __launch_bounds__(256) void wT4_kernel(
    const float* __restrict__ W0, const float* __restrict__ W1,
    const float* __restrict__ W2, const float* __restrict__ W3,
    ushort* __restrict__ T0, ushort* __restrict__ T1,
    ushort* __restrict__ T2, ushort* __restrict__ T3) {
  __shared__ ushort tt[64][72];
  const int z = blockIdx.z;
  const float* W = (z == 0) ? W0 : (z == 1) ? W1 : (z == 2) ? W2 : W3;
  ushort*     WT = (z == 0) ? T0 : (z == 1) ? T1 : (z == 2) ? T2 : T3;
  const int t = threadIdx.x;
  const int k0 = blockIdx.y * 64, n0 = blockIdx.x * 64;
#pragma unroll
  for (int c = 0; c < 4; ++c) {
    int k = c * 16 + (t >> 4);
    float4 f = *(const float4*)(W + (size_t)(k0 + k) * 1024 + n0 + (t & 15) * 4);
    unsigned int p01 = pkbf(f.x, f.y), p23 = pkbf(f.z, f.w);
    tt[(t & 15) * 4 + 0][k] = lo16(p01);
    tt[(t & 15) * 4 + 1][k] = hi16(p01);
    tt[(t & 15) * 4 + 2][k] = lo16(p23);
    tt[(t & 15) * 4 + 3][k] = hi16(p23);
  }
  __syncthreads();
#pragma unroll
  for (int p = 0; p < 2; ++p) {
    int n = p * 32 + (t >> 3);
    *(uint4*)(WT + afi(n0 + n, k0 + (t & 7) * 8)) = *(const uint4*)(&tt[n][(t & 7) * 8]);
  }
}

// Fused Q/K/V projection GEMM, m97-style: AF operands, global_load_lds staging.
// z=0: QW bf16 row-major; z=1: KF attn-fragments; z=2: VF attn-fragments.
__global__ __launch_bounds__(256) void gemm_qkv_kernel(
    const ushort* __restrict__ Aq, const ushort* __restrict__ Ak, const ushort* __restrict__ Av,
    const ushort* __restrict__ BTq, const ushort* __restrict__ BTk, const ushort* __restrict__ BTv,
    ushort* __restrict__ Cq, ushort* __restrict__ Ck, ushort* __restrict__ Cv) {
  __shared__ ushort lsA[4096];
  __shared__ ushort lsB[4096];
  const int z = blockIdx.z;
  const ushort* A  = (z == 0) ? Aq  : (z == 1) ? Ak  : Av;
  const ushort* BT = (z == 0) ? BTq : (z == 1) ? BTk : BTv;
  ushort*       Cp = (z == 0) ? Cq  : (z == 1) ? Ck  : Cv;

  const int tid  = threadIdx.x;
  const int w    = tid >> 6, lane = tid & 63, qd = lane >> 4, ln = lane & 15;
  const int rw   = w >> 1, cw = w & 1;
  const int mb   = blockIdx.y, nb = blockIdx.x;
  const int m0   = mb * 128, n0 = nb * 128;

  f32x4 acc[16];
#pragma unroll
  for (int i = 0; i < 16; ++i) acc[i] = (f32x4){0.f, 0.f, 0.f, 0.f};

  for (int kb = 0; kb < 32; ++kb) {
    const ushort* Ab = A  + ((size_t)(mb * 32 + kb) << 12);
    const ushort* Bb = BT + ((size_t)(nb * 32 + kb) << 12);
    const int c0 = 2 * w;
    gl_lds16(Ab + ((size_t)c0 << 9) + lane * 8,        lsA + (c0 << 9));
    gl_lds16(Ab + ((size_t)(c0 + 1) << 9) + lane * 8,  lsA + ((c0 + 1) << 9));
    gl_lds16(Bb + ((size_t)c0 << 9) + lane * 8,        lsB + (c0 << 9));
    gl_lds16(Bb + ((size_t)(c0 + 1) << 9) + lane * 8,  lsB + ((c0 + 1) << 9));
    __syncthreads();
    bf16x8 afr[4], bfr[4];
#pragma unroll
    for (int am = 0; am < 4; ++am)
      afr[am] = *(const bf16x8*)(lsA + ((rw * 4 + am) << 9) + lane * 8);
#pragma unroll
    for (int bn = 0; bn < 4; ++bn)
      bfr[bn] = *(const bf16x8*)(lsB + ((cw * 4 + bn) << 9) + lane * 8);
#pragma unroll
    for (int am = 0; am < 4; ++am)
#pragma unroll
      for (int bn = 0; bn < 4; ++bn)
        acc[am * 4 + bn] = __builtin_amdgcn_mfma_f32_16x16x32_bf16(afr[am], bfr[bn], acc[am * 4 + bn], 0, 0, 0);
    __syncthreads();
  }
#pragma unroll
  for (int am = 0; am < 4; ++am)
#pragma unroll
    for (int bn = 0; bn < 4; ++bn) {
      const int rbase = m0 + rw * 64 + am * 16 + qd * 4;
      const int colg  = n0 + cw * 64 + bn * 16 + ln;
      const unsigned int p01 = pkbf(acc[am * 4 + bn][0], acc[am * 4 + bn][1]);
      const unsigned int p23 = pkbf(acc[am * 4 + bn][2], acc[am * 4 + bn][3]);
      if (z == 0) {
        Cp[(size_t)(rbase + 0) * 1024 + colg] = lo16(p01);
        Cp[(size_t)(rbase + 1) * 1024 + colg] = hi16(p01);
        Cp[(size_t)(rbase + 2) * 1024 + colg] = lo16(p23);
        Cp[(size_t)(rbase + 3) * 1024 + colg] = hi16(p23);
      } else if (z == 1) {
        const int bh  = rbase >> 6;
        const int ki0 = rbase & 63;
        const int jg  = colg >> 4;
        const int ph  = ki0 >> 5;
        const int lanep = ((ki0 >> 3) & 3) * 16 + (colg & 15);
        const int jj0 = ki0 & 7;
        uint2 uu; uu.x = p01; uu.y = p23;
        *(uint2*)(Cp + (size_t)bh * 65536 + (size_t)((jg * 2 + ph) * 64 + lanep) * 8 + jj0) = uu;
      } else {
        const int bh = rbase >> 6;
        const int llow = colg >> 6, dd = colg & 63;
        const int g = dd >> 4, lnf = dd & 15;
        const ushort vals[4] = {lo16(p01), hi16(p01), lo16(p23), hi16(p23)};
#pragma unroll
        for (int r = 0; r < 4; ++r) {
          int l = ((rbase + r) & 63) * 16 + llow;
          int ks = l >> 5;
          int lanep = ((l >> 3) & 3) * 16 + lnf;
          int jj = l & 7;
          Cp[(size_t)bh * 65536 + (size_t)((g * 32 + ks) * 64 + lanep) * 8 + jj] = vals[r];
        }
      }
    }
}

// Merge GEMM, in-block split-K (8 waves), m97-style staging. A and BT in AF layout.
__global__ __launch_bounds__(512) void gemm_mg_kernel(const ushort* __restrict__ A,
                                                      const ushort* __restrict__ BT,
                                                      float* __restrict__ Cp) {
  __shared__ ushort lsA[2][4096];
  __shared__ ushort lsB[2][4096];
  __shared__ float  mgred[256 * 33];
  const int tid  = threadIdx.x;
  const int w    = tid >> 6, lane = tid & 63, qd = lane >> 4, ln = lane & 15;
  const int kh   = w >> 2, q = w & 3;
  const int rw   = q >> 1, cw = q & 1;
  const int mb   = blockIdx.y, nb = blockIdx.x;
  const int m0   = mb * 128, n0 = nb * 128;

  f32x4 acc[16];
#pragma unroll
  for (int i = 0; i < 16; ++i) acc[i] = (f32x4){0.f, 0.f, 0.f, 0.f};

  for (int kb = 0; kb < 16; ++kb) {
    const int kbi = kh * 16 + kb;
    const ushort* Ab = A  + ((size_t)(mb * 32 + kbi) << 12);
    const ushort* Bb = BT + ((size_t)(nb * 32 + kbi) << 12);
    const int c0 = 2 * q;
    gl_lds16(Ab + ((size_t)c0 << 9) + lane * 8,        lsA[kh] + (c0 << 9));
    gl_lds16(Ab + ((size_t)(c0 + 1) << 9) + lane * 8,  lsA[kh] + ((c0 + 1) << 9));
    gl_lds16(Bb + ((size_t)c0 << 9) + lane * 8,        lsB[kh] + (c0 << 9));
    gl_lds16(Bb + ((size_t)(c0 + 1) << 9) + lane * 8,  lsB[kh] + ((c0 + 1) << 9));
    __syncthreads();
    bf16x8 afr[4], bfr[4];
#pragma unroll
    for (int am = 0; am < 4; ++am)
      afr[am] = *(const bf16x8*)(lsA[kh] + ((rw * 4 + am) << 9) + lane * 8);
#pragma unroll
    for (int bn = 0; bn < 4; ++bn)
      bfr[bn] = *(const bf16x8*)(lsB[kh] + ((cw * 4 + bn) << 9) + lane * 8);
#pragma unroll
    for (int am = 0; am < 4; ++am)
#pragma unroll
      for (int bn = 0; bn < 4; ++bn)
        acc[am * 4 + bn] = __builtin_amdgcn_mfma_f32_16x16x32_bf16(afr[am], bfr[bn], acc[am * 4 + bn], 0, 0, 0);
    __syncthreads();
  }

  for (int half = 0; half < 2; ++half) {
    __syncthreads();
    if (w >= 4) {
      const int base = ((w - 4) * 64 + lane) * 33;
#pragma unroll
      for (int i = 0; i < 8; ++i)
#pragma unroll
        for (int c = 0; c < 4; ++c) mgred[base + i * 4 + c] = acc[half * 8 + i][c];
    }
    __syncthreads();
    if (w < 4) {
      const int base = (w * 64 + lane) * 33;
#pragma unroll
      for (int i = 0; i < 8; ++i)
#pragma unroll
        for (int c = 0; c < 4; ++c) acc[half * 8 + i][c] += mgred[base + i * 4 + c];
    }
  }
  if (w < 4) {
#pragma unroll
    for (int am = 0; am < 4; ++am)
#pragma unroll
      for (int bn = 0; bn < 4; ++bn) {
        const int rbase = m0 + rw * 64 + am * 16 + qd * 4;
        const int colg  = n0 + cw * 64 + bn * 16 + ln;
#pragma unroll
        for (int r = 0; r < 4; ++r)
          Cp[(size_t)(rbase + r) * 1024 + colg] = acc[am * 4 + bn][r];
      }
  }
}

// Fused relative attention — 32-row Q-tile version.
// Per block: 32 Q rows x full K (1024). 8 waves: QK^T/QEr by column slab (w*128),
// PV by (row-half rh = w>>2, col-group g = w&3), full-K per wave (no split-K reduction).
// QEr region (rows 0..32, stride 1025) is XOR-swizzled (SZ); P region (stride 1048) identity.
// The two regions share bytes but are barrier-separated epochs.
__global__ __launch_bounds__(512, 4) void attn_kernel(
    const ushort* __restrict__ QW, const ushort* __restrict__ KF,
    const ushort* __restrict__ VF, const ushort* __restrict__ ErF,
    ushort* __restrict__ Om) {
  __shared__ ushort qflat[33856];   // QEr: 33 rows @ stride 1025 (swizzled); P: 32 rows @ stride 1048
  __shared__ float  stats[2][8][32];

  const int tid  = threadIdx.x;
  const int w    = tid >> 6;
  const int lane = tid & 63;
  const int qd   = lane >> 4;
  const int ln   = lane & 15;
  const int bh   = blockIdx.y;
  const int i0   = blockIdx.x << 5;           // 32-row tiles
  const ushort* q  = QW + ((size_t)bh << 16);
  const ushort* kf = KF + ((size_t)bh << 16);
  const ushort* vf = VF + ((size_t)bh << 16);

  if (tid < 33) qflat[SZ(tid * 1025 + 1024)] = 0;   // pad-column zeros

  bf16x8 a00 = *(const bf16x8*)(q + (size_t)(i0 + ln) * 64 + qd * 8);
  bf16x8 a01 = *(const bf16x8*)(q + (size_t)(i0 + ln) * 64 + 32 + qd * 8);
  bf16x8 a10 = *(const bf16x8*)(q + (size_t)(i0 + 16 + ln) * 64 + qd * 8);
  bf16x8 a11 = *(const bf16x8*)(q + (size_t)(i0 + 16 + ln) * 64 + 32 + qd * 8);
  const int row32 = (i0 + 32 > 1023) ? 1023 : i0 + 32;
  bf16x8 a20 = *(const bf16x8*)(q + (size_t)row32 * 64 + qd * 8);
  bf16x8 a21 = *(const bf16x8*)(q + (size_t)row32 * 64 + 32 + qd * 8);

  const int jg0 = w * 8;

  // ---- phase 0: QEr (rows 0..31 + boundary row 32)
#pragma unroll
  for (int f = 0; f < 8; ++f) {
    const int jg = jg0 + f;
    bf16x8 b0 = *(const bf16x8*)(ErF + (size_t)((jg * 2 + 0) * 64 + lane) * 8);
    bf16x8 b1 = *(const bf16x8*)(ErF + (size_t)((jg * 2 + 1) * 64 + lane) * 8);
    f32x4 acc0 = {0.f, 0.f, 0.f, 0.f};
    acc0 = __builtin_amdgcn_mfma_f32_16x16x32_bf16(a00, b0, acc0, 0, 0, 0);
    acc0 = __builtin_amdgcn_mfma_f32_16x16x32_bf16(a01, b1, acc0, 0, 0, 0);
    f32x4 acc1 = {0.f, 0.f, 0.f, 0.f};
    acc1 = __builtin_amdgcn_mfma_f32_16x16x32_bf16(a10, b0, acc1, 0, 0, 0);
    acc1 = __builtin_amdgcn_mfma_f32_16x16x32_bf16(a11, b1, acc1, 0, 0, 0);
    const int m = jg * 16 + ln;
#pragma unroll
    for (int r = 0; r < 4; ++r) {
      qflat[SZ((qd * 4 + r) * 1025 + m)]        = f2bf(acc0[r]);
      qflat[SZ((16 + qd * 4 + r) * 1025 + m)]   = f2bf(acc1[r]);
    }
    if (jg * 16 <= 990 - i0) {
      f32x4 ac2 = {0.f, 0.f, 0.f, 0.f};
      ac2 = __builtin_amdgcn_mfma_f32_16x16x32_bf16(a20, b0, ac2, 0, 0, 0);
      ac2 = __builtin_amdgcn_mfma_f32_16x16x32_bf16(a21, b1, ac2, 0, 0, 0);
      if (qd == 0) qflat[SZ(32 * 1025 + m)] = f2bf(ac2[0]);
    }
  }

  // ---- phase 1: S = q @ kT (both row groups)
  f32x4 sfr0[8], sfr1[8];
#pragma unroll
  for (int f = 0; f < 8; ++f) {
    const int jg = jg0 + f;
    bf16x8 b0 = *(const bf16x8*)(kf + (size_t)((jg * 2 + 0) * 64 + lane) * 8);
    bf16x8 b1 = *(const bf16x8*)(kf + (size_t)((jg * 2 + 1) * 64 + lane) * 8);
    f32x4 acc = {0.f, 0.f, 0.f, 0.f};
    acc = __builtin_amdgcn_mfma_f32_16x16x32_bf16(a00, b0, acc, 0, 0, 0);
    acc = __builtin_amdgcn_mfma_f32_16x16x32_bf16(a01, b1, acc, 0, 0, 0);
    sfr0[f] = acc;
    f32x4 ac1 = {0.f, 0.f, 0.f, 0.f};
    ac1 = __builtin_amdgcn_mfma_f32_16x16x32_bf16(a10, b0, ac1, 0, 0, 0);
    ac1 = __builtin_amdgcn_mfma_f32_16x16x32_bf16(a11, b1, ac1, 0, 0, 0);
    sfr1[f] = ac1;
  }
  __syncthreads();

  // ---- skew-add (flat gather, swizzled QEr region)
#pragma unroll
  for (int f = 0; f < 8; ++f) {
    const int cj = 1023 - i0 + w * 128 + f * 16 + ln;
#pragma unroll
    for (int r = 0; r < 4; ++r) {
      sfr0[f][r] += bf2f(qflat[SZ((qd * 4 + r) * 1024 + cj)]);
      sfr1[f][r] += bf2f(qflat[SZ((16 + qd * 4 + r) * 1024 + cj)]);
    }
  }

  // ---- row max (both groups)
  {
    float vm0[4], vm1[4];
#pragma unroll
    for (int r = 0; r < 4; ++r) {
      float m0 = sfr0[0][r], m1 = sfr1[0][r];
#pragma unroll
      for (int f = 1; f < 8; ++f) { m0 = fmaxf(m0, sfr0[f][r]); m1 = fmaxf(m1, sfr1[f][r]); }
#pragma unroll
      for (int off = 1; off < 16; off <<= 1) {
        m0 = fmaxf(m0, __shfl_xor(m0, off, 64));
        m1 = fmaxf(m1, __shfl_xor(m1, off, 64));
      }
      vm0[r] = m0; vm1[r] = m1;
    }
    if (ln == 0) {
#pragma unroll
      for (int r = 0; r < 4; ++r) {
        stats[0][w][qd * 4 + r]      = vm0[r];
        stats[0][w][16 + qd * 4 + r] = vm1[r];
      }
    }
  }
  __syncthreads();
  const float cexp = 0.18033688011112042f;   // 0.125 * log2(e)
  float gm20[4], gm21[4];
#pragma unroll
  for (int r = 0; r < 4; ++r) {
    float m0 = stats[0][0][qd * 4 + r], m1 = stats[0][0][16 + qd * 4 + r];
#pragma unroll
    for (int ww = 1; ww < 8; ++ww) {
      m0 = fmaxf(m0, stats[0][ww][qd * 4 + r]);
      m1 = fmaxf(m1, stats[0][ww][16 + qd * 4 + r]);
    }
    gm20[r] = -m0 * cexp; gm21[r] = -m1 * cexp;
  }

  // ---- exp2, sums, P at stride 1048 (identity addressing)
  float vs0[4] = {0.f, 0.f, 0.f, 0.f};
  float vs1[4] = {0.f, 0.f, 0.f, 0.f};
#pragma unroll
  for (int f = 0; f < 8; ++f) {
    const int j = w * 128 + f * 16 + ln;
#pragma unroll
    for (int r = 0; r < 4; ++r) {
      const float e0 = exp2f(fmaf(sfr0[f][r], cexp, gm20[r]));
      const float e1 = exp2f(fmaf(sfr1[f][r], cexp, gm21[r]));
      vs0[r] += e0; vs1[r] += e1;
      qflat[(qd * 4 + r) * 1048 + j]        = f2bf(e0);
      qflat[(16 + qd * 4 + r) * 1048 + j]   = f2bf(e1);
    }
  }
#pragma unroll
  for (int r = 0; r < 4; ++r) {
    float s0 = vs0[r], s1 = vs1[r];
#pragma unroll
    for (int off = 1; off < 16; off <<= 1) {
      s0 += __shfl_xor(s0, off, 64);
      s1 += __shfl_xor(s1, off, 64);
    }
    if (ln == 0) { stats[1][w][qd * 4 + r] = s0; stats[1][w][16 + qd * 4 + r] = s1; }
  }
  __syncthreads();
  float rrl0[4], rrl1[4];
#pragma unroll
  for (int r = 0; r < 4; ++r) {
    float s0 = 0.f, s1 = 0.f;
#pragma unroll
    for (int ww = 0; ww < 8; ++ww) {
      s0 += stats[1][ww][qd * 4 + r];
      s1 += stats[1][ww][16 + qd * 4 + r];
    }
    rrl0[r] = 1.0f / s0; rrl1[r] = 1.0f / s1;
  }

  // ---- phase 3: O = P @ v — per wave: rows rh*16..rh*16+15, cols g*16..g*16+15, full K.
  const int g = w & 3, rh = w >> 2;
  f32x4 oacc0 = {0.f, 0.f, 0.f, 0.f};
  f32x4 oacc1 = {0.f, 0.f, 0.f, 0.f};
#pragma unroll
  for (int ks = 0; ks < 32; ks += 2) {
    bf16x8 ap0 = *(const bf16x8*)(qflat + (rh * 16 + ln) * 1048 + ks * 32 + qd * 8);
    bf16x8 bv0 = *(const bf16x8*)(vf + (size_t)((g * 32 + ks) * 64 + lane) * 8);
    oacc0 = __builtin_amdgcn_mfma_f32_16x16x32_bf16(ap0, bv0, oacc0, 0, 0, 0);
    bf16x8 ap1 = *(const bf16x8*)(qflat + (rh * 16 + ln) * 1048 + (ks + 1) * 32 + qd * 8);
    bf16x8 bv1 = *(const bf16x8*)(vf + (size_t)((g * 32 + ks + 1) * 64 + lane) * 8);
    oacc1 = __builtin_amdgcn_mfma_f32_16x16x32_bf16(ap1, bv1, oacc1, 0, 0, 0);
  }
  f32x4 oacc = oacc0 + oacc1;

  // ---- write O in AF layout (all 8 waves; disjoint tiles)
  {
    const int b = bh >> 4, h = bh & 15;
    const int kg = h * 64 + g * 16 + ln;
    const int mbase = b * 1024 + i0 + rh * 16;
    ushort* ob = Om + (((size_t)((mbase >> 7) * 32 + (kg >> 5)) * 8 + ((mbase >> 4) & 7)) << 9)
               + ((((kg >> 3) & 3) * 16 + qd * 4) << 3) + (kg & 7);
    const float o0 = oacc[0] * (rh ? rrl1[0] : rrl0[0]);
    const float o1 = oacc[1] * (rh ? rrl1[1] : rrl0[1]);
    const float o2 = oacc[2] * (rh ? rrl1[2] : rrl0[2]);
    const float o3 = oacc[3] * (rh ? rrl1[3] : rrl0[3]);
    const unsigned int p01 = pkbf(o0, o1);
    const unsigned int p23 = pkbf(o2, o3);
    ob[0]  = lo16(p01);
    ob[8]  = hi16(p01);
    ob[16] = lo16(p23);
    ob[24] = hi16(p23);
  }
}

extern "C" void kernel_launch(void* const* d_in, const int* in_sizes, int n_in,
                              void* d_out, int out_size, void* d_ws, size_t ws_size,
                              hipStream_t stream) {
  const float* query = (const float*)d_in[0];
  const float* key   = (const float*)d_in[1];
  const float* value = (const float*)d_in[2];
  const float* WQ    = (const float*)d_in[3];
  const float* WK    = (const float*)d_in[4];
  const float* WV    = (const float*)d_in[5];
  const float* Er    = (const float*)d_in[6];
  const float* WM    = (const float*)d_in[7];
  float* out = (float*)d_out;

  // workspace (ushort units): QW,KF,VF,O 4M each; ErF 64K; 4 WT 1M each; KB,VB 4M each.
  // QB (bf16 AF query) aliases O: consumed by qkv GEMM before attn writes O (AF).
  ushort* QW  = (ushort*)d_ws;
  ushort* KF  = QW  + (size_t)4096 * 1024;
  ushort* VF  = KF  + (size_t)4096 * 1024;
  ushort* O   = VF  + (size_t)4096 * 1024;
  ushort* ErF = O   + (size_t)4096 * 1024;
  ushort* WTQ = ErF + (size_t)65536;
  ushort* WTK = WTQ + (size_t)1024 * 1024;
  ushort* WTV = WTK + (size_t)1024 * 1024;
  ushort* WTM = WTV + (size_t)1024 * 1024;
  ushort* KB  = WTM + (size_t)1024 * 1024;
  ushort* VB  = KB  + (size_t)4096 * 1024;
  ushort* QB  = O;   // alias

  cvt3_kernel<<<dim3(2048, 3), 256, 0, stream>>>(query, key, value, QB, KB, VB);
  wT4_kernel<<<dim3(16, 16, 4), 256, 0, stream>>>(WQ, WK, WV, WM, WTQ, WTK, WTV, WTM);
  erF_kernel<<<32, 256, 0, stream>>>(Er, ErF);

  gemm_qkv_kernel<<<dim3(8, 32, 3), 256, 0, stream>>>(QB, KB, VB,
                                                      WTQ, WTK, WTV,
                                                      QW, KF, VF);

  attn_kernel<<<dim3(32, 64), 512, 0, stream>>>(QW, KF, VF, ErF, O);

  gemm_mg_kernel<<<dim3(8, 32), 512, 0, stream>>>(O, WTM, out);
}

// Round 5
// 273.966 us; speedup vs baseline: 1.0229x; 1.0229x over previous
//
#include <hip/hip_runtime.h>

#define H_  16
#define L_  1024
#define D_  1024
#define DH  64

typedef short bf16x8 __attribute__((ext_vector_type(8)));
typedef float f32x4  __attribute__((ext_vector_type(4)));

__device__ __forceinline__ ushort f2bf(float f) {
  union { float f; unsigned int u; } x; x.f = f;
  unsigned int u = x.u;
  u = (u + 0x7fffu + ((u >> 16) & 1u)) >> 16;   // RNE
  return (ushort)u;
}
__device__ __forceinline__ float bf2f(ushort s) {
  union { unsigned int u; float f; } x; x.u = ((unsigned int)s) << 16;
  return x.f;
}

// Software packed f32->bf16 (round-half-up) -> [bf16(b)<<16 | bf16(a)].
__device__ __forceinline__ unsigned int pkbf(float a, float b) {
  union { float f; unsigned int u; } xa, xb; xa.f = a; xb.f = b;
  unsigned int ua = xa.u + 0x8000u;
  unsigned int ub = xb.u + 0x8000u;
  return (ua >> 16) | (ub & 0xffff0000u);
}
__device__ __forceinline__ ushort lo16(unsigned int v) { return (ushort)v; }
__device__ __forceinline__ ushort hi16(unsigned int v) { return (ushort)(v >> 16); }

// QEr-region swizzle (ushort index): XOR bits[5:4] with bits[13:12]. Involution.
// Applied to ALL QEr-epoch accesses (stores, zero-init, skew reads).
// Skew-read groups (qd) sat on the same 8 banks (row stride 4*1024 ush == 0 mod 32
// banks -> 4-way conflict); the XOR gives each qd group a distinct 8-bank window.
__device__ __forceinline__ int SZ(int F) { return F ^ (((F >> 12) & 3) << 4); }

// Fragment-interleaved (AF) layout for an M x 1024 bf16 matrix:
// chunk (mb=m>>7, kb=k>>5, am=(m>>4)&7) of 512 ushort; within: lane=((k>>3)&3)*16+(m&15), jj=k&7.
__device__ __forceinline__ size_t afi(int m, int k) {
  return (((size_t)((m >> 7) * 32 + (k >> 5)) * 8 + ((m >> 4) & 7)) << 9)
       + ((size_t)((((k >> 3) & 3) << 4) + (m & 15)) << 3) + (k & 7);
}

// async global->LDS 16B per lane: dst = (wave-uniform) l + lane*16, src = per-lane g.
__device__ __forceinline__ void gl_lds16(const ushort* g, ushort* l) {
  __builtin_amdgcn_global_load_lds(
      (const __attribute__((address_space(1))) void*)g,
      (__attribute__((address_space(3))) void*)l, 16, 0, 0);
}

// q/k/v fp32 row-major -> bf16 AF layout.
__global__ __launch_bounds__(256) void cvt3_kernel(
    const float* __restrict__ q, const float* __restrict__ k, const float* __restrict__ v,
    ushort* __restrict__ qb, ushort* __restrict__ kb, ushort* __restrict__ vb) {
  const int z = blockIdx.y;
  const float* in = (z == 0) ? q : (z == 1) ? k : v;
  ushort* out = (z == 0) ? qb : (z == 1) ? kb : vb;
  int idx = (blockIdx.x * 256 + threadIdx.x) * 8;
  int m = idx >> 10, kk = idx & 1023;
  float4 f0 = *(const float4*)(in + idx);
  float4 f1 = *(const float4*)(in + idx + 4);
  uint4 o;
  o.x = pkbf(f0.x, f0.y); o.y = pkbf(f0.z, f0.w);
  o.z = pkbf(f1.x, f1.y); o.w = pkbf(f1.z, f1.w);
  *(uint4*)(out + afi(m, kk)) = o;
}

// Er fp32 [1024][64] -> ErF fragment-interleaved bf16 (attn-style fragments).
__global__ __launch_bounds__(256) void erF_kernel(const float* __restrict__ Er,
                                                  ushort* __restrict__ ErF) {
  int t = blockIdx.x * 256 + threadIdx.x;   // [0, 8192)
  int lane = t & 63, ph = (t >> 6) & 1, jg = t >> 7;
  int m = jg * 16 + (lane & 15);
  int k = ph * 32 + (lane >> 4) * 8;
  float4 f0 = *(const float4*)(Er + m * 64 + k);
  float4 f1 = *(const float4*)(Er + m * 64 + k + 4);
  uint4 o;
  o.x = pkbf(f0.x, f0.y); o.y = pkbf(f0.z, f0.w);
  o.z = pkbf(f1.x, f1.y); o.w = pkbf(f1.z, f1.w);
  *(uint4*)(ErF + t * 8) = o;
}

// 4 weight transposes fused: W fp32 [k][n] -> WT bf16 AF layout of BT[n][k].
__global__ __launch_bounds__(256) void wT4_kernel(
    const float* __restrict__ W0, const float* __restrict__ W1,
    const float* __restrict__ W2, const float* __restrict__ W3,
    ushort* __restrict__ T0, ushort* __restrict__ T1,
    ushort* __restrict__ T2, ushort* __restrict__ T3) {
  __shared__ ushort tt[64][72];
  const int z = blockIdx.z;
  const float* W = (z == 0) ? W0 : (z == 1) ? W1 : (z == 2) ? W2 : W3;
  ushort*     WT = (z == 0) ? T0 : (z == 1) ? T1 : (z == 2) ? T2 : T3;
  const int t = threadIdx.x;
  const int k0 = blockIdx.y * 64, n0 = blockIdx.x * 64;
#pragma unroll
  for (int c = 0; c < 4; ++c) {
    int k = c * 16 + (t >> 4);
    float4 f = *(const float4*)(W + (size_t)(k0 + k) * 1024 + n0 + (t & 15) * 4);
    unsigned int p01 = pkbf(f.x, f.y), p23 = pkbf(f.z, f.w);
    tt[(t & 15) * 4 + 0][k] = lo16(p01);
    tt[(t & 15) * 4 + 1][k] = hi16(p01);
    tt[(t & 15) * 4 + 2][k] = lo16(p23);
    tt[(t & 15) * 4 + 3][k] = hi16(p23);
  }
  __syncthreads();
#pragma unroll
  for (int p = 0; p < 2; ++p) {
    int n = p * 32 + (t >> 3);
    *(uint4*)(WT + afi(n0 + n, k0 + (t & 7) * 8)) = *(const uint4*)(&tt[n][(t & 7) * 8]);
  }
}

// Fused Q/K/V projection GEMM, m97-style: AF operands, global_load_lds staging.
// z=0: QW bf16 row-major; z=1: KF attn-fragments; z=2: VF attn-fragments.
__global__ __launch_bounds__(256) void gemm_qkv_kernel(
    const ushort* __restrict__ Aq, const ushort* __restrict__ Ak, const ushort* __restrict__ Av,
    const ushort* __restrict__ BTq, const ushort* __restrict__ BTk, const ushort* __restrict__ BTv,
    ushort* __restrict__ Cq, ushort* __restrict__ Ck, ushort* __restrict__ Cv) {
  __shared__ ushort lsA[4096];
  __shared__ ushort lsB[4096];
  const int z = blockIdx.z;
  const ushort* A  = (z == 0) ? Aq  : (z == 1) ? Ak  : Av;
  const ushort* BT = (z == 0) ? BTq : (z == 1) ? BTk : BTv;
  ushort*       Cp = (z == 0) ? Cq  : (z == 1) ? Ck  : Cv;

  const int tid  = threadIdx.x;
  const int w    = tid >> 6, lane = tid & 63, qd = lane >> 4, ln = lane & 15;
  const int rw   = w >> 1, cw = w & 1;
  const int mb   = blockIdx.y, nb = blockIdx.x;
  const int m0   = mb * 128, n0 = nb * 128;

  f32x4 acc[16];
#pragma unroll
  for (int i = 0; i < 16; ++i) acc[i] = (f32x4){0.f, 0.f, 0.f, 0.f};

  for (int kb = 0; kb < 32; ++kb) {
    const ushort* Ab = A  + ((size_t)(mb * 32 + kb) << 12);
    const ushort* Bb = BT + ((size_t)(nb * 32 + kb) << 12);
    const int c0 = 2 * w;
    gl_lds16(Ab + ((size_t)c0 << 9) + lane * 8,        lsA + (c0 << 9));
    gl_lds16(Ab + ((size_t)(c0 + 1) << 9) + lane * 8,  lsA + ((c0 + 1) << 9));
    gl_lds16(Bb + ((size_t)c0 << 9) + lane * 8,        lsB + (c0 << 9));
    gl_lds16(Bb + ((size_t)(c0 + 1) << 9) + lane * 8,  lsB + ((c0 + 1) << 9));
    __syncthreads();
    bf16x8 afr[4], bfr[4];
#pragma unroll
    for (int am = 0; am < 4; ++am)
      afr[am] = *(const bf16x8*)(lsA + ((rw * 4 + am) << 9) + lane * 8);
#pragma unroll
    for (int bn = 0; bn < 4; ++bn)
      bfr[bn] = *(const bf16x8*)(lsB + ((cw * 4 + bn) << 9) + lane * 8);
#pragma unroll
    for (int am = 0; am < 4; ++am)
#pragma unroll
      for (int bn = 0; bn < 4; ++bn)
        acc[am * 4 + bn] = __builtin_amdgcn_mfma_f32_16x16x32_bf16(afr[am], bfr[bn], acc[am * 4 + bn], 0, 0, 0);
    __syncthreads();
  }
#pragma unroll
  for (int am = 0; am < 4; ++am)
#pragma unroll
    for (int bn = 0; bn < 4; ++bn) {
      const int rbase = m0 + rw * 64 + am * 16 + qd * 4;
      const int colg  = n0 + cw * 64 + bn * 16 + ln;
      const unsigned int p01 = pkbf(acc[am * 4 + bn][0], acc[am * 4 + bn][1]);
      const unsigned int p23 = pkbf(acc[am * 4 + bn][2], acc[am * 4 + bn][3]);
      if (z == 0) {
        Cp[(size_t)(rbase + 0) * 1024 + colg] = lo16(p01);
        Cp[(size_t)(rbase + 1) * 1024 + colg] = hi16(p01);
        Cp[(size_t)(rbase + 2) * 1024 + colg] = lo16(p23);
        Cp[(size_t)(rbase + 3) * 1024 + colg] = hi16(p23);
      } else if (z == 1) {
        const int bh  = rbase >> 6;
        const int ki0 = rbase & 63;
        const int jg  = colg >> 4;
        const int ph  = ki0 >> 5;
        const int lanep = ((ki0 >> 3) & 3) * 16 + (colg & 15);
        const int jj0 = ki0 & 7;
        uint2 uu; uu.x = p01; uu.y = p23;
        *(uint2*)(Cp + (size_t)bh * 65536 + (size_t)((jg * 2 + ph) * 64 + lanep) * 8 + jj0) = uu;
      } else {
        const int bh = rbase >> 6;
        const int llow = colg >> 6, dd = colg & 63;
        const int g = dd >> 4, lnf = dd & 15;
        const ushort vals[4] = {lo16(p01), hi16(p01), lo16(p23), hi16(p23)};
#pragma unroll
        for (int r = 0; r < 4; ++r) {
          int l = ((rbase + r) & 63) * 16 + llow;
          int ks = l >> 5;
          int lanep = ((l >> 3) & 3) * 16 + lnf;
          int jj = l & 7;
          Cp[(size_t)bh * 65536 + (size_t)((g * 32 + ks) * 64 + lanep) * 8 + jj] = vals[r];
        }
      }
    }
}

// Merge GEMM, in-block split-K (8 waves), m97-style staging. A and BT in AF layout.
__global__ __launch_bounds__(512) void gemm_mg_kernel(const ushort* __restrict__ A,
                                                      const ushort* __restrict__ BT,
                                                      float* __restrict__ Cp) {
  __shared__ ushort lsA[2][4096];
  __shared__ ushort lsB[2][4096];
  __shared__ float  mgred[256 * 33];
  const int tid  = threadIdx.x;
  const int w    = tid >> 6, lane = tid & 63, qd = lane >> 4, ln = lane & 15;
  const int kh   = w >> 2, q = w & 3;
  const int rw   = q >> 1, cw = q & 1;
  const int mb   = blockIdx.y, nb = blockIdx.x;
  const int m0   = mb * 128, n0 = nb * 128;

  f32x4 acc[16];
#pragma unroll
  for (int i = 0; i < 16; ++i) acc[i] = (f32x4){0.f, 0.f, 0.f, 0.f};

  for (int kb = 0; kb < 16; ++kb) {
    const int kbi = kh * 16 + kb;
    const ushort* Ab = A  + ((size_t)(mb * 32 + kbi) << 12);
    const ushort* Bb = BT + ((size_t)(nb * 32 + kbi) << 12);
    const int c0 = 2 * q;
    gl_lds16(Ab + ((size_t)c0 << 9) + lane * 8,        lsA[kh] + (c0 << 9));
    gl_lds16(Ab + ((size_t)(c0 + 1) << 9) + lane * 8,  lsA[kh] + ((c0 + 1) << 9));
    gl_lds16(Bb + ((size_t)c0 << 9) + lane * 8,        lsB[kh] + (c0 << 9));
    gl_lds16(Bb + ((size_t)(c0 + 1) << 9) + lane * 8,  lsB[kh] + ((c0 + 1) << 9));
    __syncthreads();
    bf16x8 afr[4], bfr[4];
#pragma unroll
    for (int am = 0; am < 4; ++am)
      afr[am] = *(const bf16x8*)(lsA[kh] + ((rw * 4 + am) << 9) + lane * 8);
#pragma unroll
    for (int bn = 0; bn < 4; ++bn)
      bfr[bn] = *(const bf16x8*)(lsB[kh] + ((cw * 4 + bn) << 9) + lane * 8);
#pragma unroll
    for (int am = 0; am < 4; ++am)
#pragma unroll
      for (int bn = 0; bn < 4; ++bn)
        acc[am * 4 + bn] = __builtin_amdgcn_mfma_f32_16x16x32_bf16(afr[am], bfr[bn], acc[am * 4 + bn], 0, 0, 0);
    __syncthreads();
  }

  for (int half = 0; half < 2; ++half) {
    __syncthreads();
    if (w >= 4) {
      const int base = ((w - 4) * 64 + lane) * 33;
#pragma unroll
      for (int i = 0; i < 8; ++i)
#pragma unroll
        for (int c = 0; c < 4; ++c) mgred[base + i * 4 + c] = acc[half * 8 + i][c];
    }
    __syncthreads();
    if (w < 4) {
      const int base = (w * 64 + lane) * 33;
#pragma unroll
      for (int i = 0; i < 8; ++i)
#pragma unroll
        for (int c = 0; c < 4; ++c) acc[half * 8 + i][c] += mgred[base + i * 4 + c];
    }
  }
  if (w < 4) {
#pragma unroll
    for (int am = 0; am < 4; ++am)
#pragma unroll
      for (int bn = 0; bn < 4; ++bn) {
        const int rbase = m0 + rw * 64 + am * 16 + qd * 4;
        const int colg  = n0 + cw * 64 + bn * 16 + ln;
#pragma unroll
        for (int r = 0; r < 4; ++r)
          Cp[(size_t)(rbase + r) * 1024 + colg] = acc[am * 4 + bn][r];
      }
  }
}

// Fused relative attention — 16-row Q-tile (R3 structure) + QEr-region XOR swizzle
// + max-free softmax (shift-invariant; S/8 range ~[-15,15], exp stays in fp32 range).
// Barrier after skew-add is kept: P stores overwrite QEr bytes, epoch must be sealed.
__global__ __launch_bounds__(512, 4) void attn_kernel(
    const ushort* __restrict__ QW, const ushort* __restrict__ KF,
    const ushort* __restrict__ VF, const ushort* __restrict__ ErF,
    ushort* __restrict__ Om) {
  __shared__ ushort qflat[17440];    // QEr rows 0..16 @ r*1025 (swizzled); P rows @ r*1048 (identity)
  __shared__ float  red[4][64][4];
  __shared__ float  stats[8][16];

  const int tid  = threadIdx.x;
  const int w    = tid >> 6;
  const int lane = tid & 63;
  const int qd   = lane >> 4;
  const int ln   = lane & 15;
  const int bh   = blockIdx.y;
  const int i0   = blockIdx.x << 4;
  const ushort* q  = QW + ((size_t)bh << 16);
  const ushort* kf = KF + ((size_t)bh << 16);
  const ushort* vf = VF + ((size_t)bh << 16);

  if (tid < 17) qflat[SZ(tid * 1025 + 1024)] = 0;   // the j==i+1 zeros

  bf16x8 a00 = *(const bf16x8*)(q + (size_t)(i0 + ln) * 64 + qd * 8);
  bf16x8 a01 = *(const bf16x8*)(q + (size_t)(i0 + ln) * 64 + 32 + qd * 8);
  const int row16 = (i0 + 16 > 1023) ? 1023 : i0 + 16;
  bf16x8 a10 = *(const bf16x8*)(q + (size_t)row16 * 64 + qd * 8);
  bf16x8 a11 = *(const bf16x8*)(q + (size_t)row16 * 64 + 32 + qd * 8);

  const int jg0 = w * 8;

  // ---- phase 0: QEr (stores via SZ)
#pragma unroll
  for (int f = 0; f < 8; ++f) {
    const int jg = jg0 + f;
    bf16x8 b0 = *(const bf16x8*)(ErF + (size_t)((jg * 2 + 0) * 64 + lane) * 8);
    bf16x8 b1 = *(const bf16x8*)(ErF + (size_t)((jg * 2 + 1) * 64 + lane) * 8);
    f32x4 acc = {0.f, 0.f, 0.f, 0.f};
    acc = __builtin_amdgcn_mfma_f32_16x16x32_bf16(a00, b0, acc, 0, 0, 0);
    acc = __builtin_amdgcn_mfma_f32_16x16x32_bf16(a01, b1, acc, 0, 0, 0);
    const int m = jg * 16 + ln;
    const unsigned int p01 = pkbf(acc[0], acc[1]);
    const unsigned int p23 = pkbf(acc[2], acc[3]);
    qflat[SZ((qd * 4 + 0) * 1025 + m)] = lo16(p01);
    qflat[SZ((qd * 4 + 1) * 1025 + m)] = hi16(p01);
    qflat[SZ((qd * 4 + 2) * 1025 + m)] = lo16(p23);
    qflat[SZ((qd * 4 + 3) * 1025 + m)] = hi16(p23);
    if (jg * 16 <= 1006 - i0) {
      f32x4 ac2 = {0.f, 0.f, 0.f, 0.f};
      ac2 = __builtin_amdgcn_mfma_f32_16x16x32_bf16(a10, b0, ac2, 0, 0, 0);
      ac2 = __builtin_amdgcn_mfma_f32_16x16x32_bf16(a11, b1, ac2, 0, 0, 0);
      if (qd == 0) qflat[SZ(16 * 1025 + m)] = f2bf(ac2[0]);
    }
  }

  // ---- phase 1: S = q @ kT
  f32x4 sfr[8];
#pragma unroll
  for (int f = 0; f < 8; ++f) {
    const int jg = jg0 + f;
    bf16x8 b0 = *(const bf16x8*)(kf + (size_t)((jg * 2 + 0) * 64 + lane) * 8);
    bf16x8 b1 = *(const bf16x8*)(kf + (size_t)((jg * 2 + 1) * 64 + lane) * 8);
    f32x4 acc = {0.f, 0.f, 0.f, 0.f};
    acc = __builtin_amdgcn_mfma_f32_16x16x32_bf16(a00, b0, acc, 0, 0, 0);
    acc = __builtin_amdgcn_mfma_f32_16x16x32_bf16(a01, b1, acc, 0, 0, 0);
    sfr[f] = acc;
  }
  __syncthreads();

  // ---- skew-add (branch-free flat gather through the swizzle)
#pragma unroll
  for (int f = 0; f < 8; ++f) {
    const int cj = 1023 - i0 + w * 128 + f * 16 + ln;
#pragma unroll
    for (int r = 0; r < 4; ++r)
      sfr[f][r] += bf2f(qflat[SZ((qd * 4 + r) * 1024 + cj)]);
  }
  __syncthreads();   // seal QEr epoch before P stores overwrite the region

  // ---- exp2 (no max subtraction), sums, P at stride 1048
  const float cexp = 0.18033688011112042f;   // 0.125 * log2(e)
  float vs[4] = {0.f, 0.f, 0.f, 0.f};
#pragma unroll
  for (int f = 0; f < 8; ++f) {
    const int j = w * 128 + f * 16 + ln;
    const float e0 = exp2f(sfr[f][0] * cexp);
    const float e1 = exp2f(sfr[f][1] * cexp);
    const float e2 = exp2f(sfr[f][2] * cexp);
    const float e3 = exp2f(sfr[f][3] * cexp);
    vs[0] += e0; vs[1] += e1; vs[2] += e2; vs[3] += e3;
    const unsigned int p01 = pkbf(e0, e1);
    const unsigned int p23 = pkbf(e2, e3);
    qflat[(qd * 4 + 0) * 1048 + j] = lo16(p01);
    qflat[(qd * 4 + 1) * 1048 + j] = hi16(p01);
    qflat[(qd * 4 + 2) * 1048 + j] = lo16(p23);
    qflat[(qd * 4 + 3) * 1048 + j] = hi16(p23);
  }
#pragma unroll
  for (int r = 0; r < 4; ++r) {
    float s = vs[r];
#pragma unroll
    for (int off = 1; off < 16; off <<= 1) s += __shfl_xor(s, off, 64);
    if (ln == 0) stats[w][qd * 4 + r] = s;
  }
  __syncthreads();
  float rrl[4];
#pragma unroll
  for (int r = 0; r < 4; ++r) {
    float s = 0.f;
#pragma unroll
    for (int ww = 0; ww < 8; ++ww) s += stats[ww][qd * 4 + r];
    rrl[r] = 1.0f / s;
  }

  // ---- phase 3: O = P @ v (split-K across wave pairs; 2 accumulate chains)
  const int g = w & 3, kh = w >> 2;
  f32x4 oacc0 = {0.f, 0.f, 0.f, 0.f};
  f32x4 oacc1 = {0.f, 0.f, 0.f, 0.f};
#pragma unroll
  for (int kc = 0; kc < 16; kc += 2) {
    const int ks0 = kh * 16 + kc;
    const int ks1 = ks0 + 1;
    bf16x8 ap0 = *(const bf16x8*)(qflat + ln * 1048 + ks0 * 32 + qd * 8);
    bf16x8 bv0 = *(const bf16x8*)(vf + (size_t)((g * 32 + ks0) * 64 + lane) * 8);
    oacc0 = __builtin_amdgcn_mfma_f32_16x16x32_bf16(ap0, bv0, oacc0, 0, 0, 0);
    bf16x8 ap1 = *(const bf16x8*)(qflat + ln * 1048 + ks1 * 32 + qd * 8);
    bf16x8 bv1 = *(const bf16x8*)(vf + (size_t)((g * 32 + ks1) * 64 + lane) * 8);
    oacc1 = __builtin_amdgcn_mfma_f32_16x16x32_bf16(ap1, bv1, oacc1, 0, 0, 0);
  }
  f32x4 oacc = oacc0 + oacc1;

  if (w >= 4) {
#pragma unroll
    for (int cc = 0; cc < 4; ++cc) red[w - 4][lane][cc] = oacc[cc];
  }
  __syncthreads();
  if (w < 4) {
    const int b = bh >> 4, h = bh & 15;
    // O in AF layout: m = b*1024 + i0 + qd*4 + r, kg = h*64 + g*16 + ln
    const int kg = h * 64 + g * 16 + ln;
    const int mbase = b * 1024 + i0;
    ushort* ob = Om + (((size_t)((mbase >> 7) * 32 + (kg >> 5)) * 8 + ((mbase >> 4) & 7)) << 9)
               + ((((kg >> 3) & 3) * 16 + qd * 4) << 3) + (kg & 7);
    const float o0 = (oacc[0] + red[w][lane][0]) * rrl[0];
    const float o1 = (oacc[1] + red[w][lane][1]) * rrl[1];
    const float o2 = (oacc[2] + red[w][lane][2]) * rrl[2];
    const float o3 = (oacc[3] + red[w][lane][3]) * rrl[3];
    const unsigned int p01 = pkbf(o0, o1);
    const unsigned int p23 = pkbf(o2, o3);
    ob[0]  = lo16(p01);
    ob[8]  = hi16(p01);
    ob[16] = lo16(p23);
    ob[24] = hi16(p23);
  }
}

extern "C" void kernel_launch(void* const* d_in, const int* in_sizes, int n_in,
                              void* d_out, int out_size, void* d_ws, size_t ws_size,
                              hipStream_t stream) {
  const float* query = (const float*)d_in[0];
  const float* key   = (const float*)d_in[1];
  const float* value = (const float*)d_in[2];
  const float* WQ    = (const float*)d_in[3];
  const float* WK    = (const float*)d_in[4];
  const float* WV    = (const float*)d_in[5];
  const float* Er    = (const float*)d_in[6];
  const float* WM    = (const float*)d_in[7];
  float* out = (float*)d_out;

  // workspace (ushort units): QW,KF,VF,O 4M each; ErF 64K; 4 WT 1M each; KB,VB 4M each.
  // QB (bf16 AF query) aliases O: consumed by qkv GEMM before attn writes O (AF).
  ushort* QW  = (ushort*)d_ws;
  ushort* KF  = QW  + (size_t)4096 * 1024;
  ushort* VF  = KF  + (size_t)4096 * 1024;
  ushort* O   = VF  + (size_t)4096 * 1024;
  ushort* ErF = O   + (size_t)4096 * 1024;
  ushort* WTQ = ErF + (size_t)65536;
  ushort* WTK = WTQ + (size_t)1024 * 1024;
  ushort* WTV = WTK + (size_t)1024 * 1024;
  ushort* WTM = WTV + (size_t)1024 * 1024;
  ushort* KB  = WTM + (size_t)1024 * 1024;
  ushort* VB  = KB  + (size_t)4096 * 1024;
  ushort* QB  = O;   // alias

  cvt3_kernel<<<dim3(2048, 3), 256, 0, stream>>>(query, key, value, QB, KB, VB);
  wT4_kernel<<<dim3(16, 16, 4), 256, 0, stream>>>(WQ, WK, WV, WM, WTQ, WTK, WTV, WTM);
  erF_kernel<<<32, 256, 0, stream>>>(Er, ErF);

  gemm_qkv_kernel<<<dim3(8, 32, 3), 256, 0, stream>>>(QB, KB, VB,
                                                      WTQ, WTK, WTV,
                                                      QW, KF, VF);

  attn_kernel<<<dim3(64, 64), 512, 0, stream>>>(QW, KF, VF, ErF, O);

  gemm_mg_kernel<<<dim3(8, 32), 512, 0, stream>>>(O, WTM, out);
}

// Round 6
// 269.800 us; speedup vs baseline: 1.0387x; 1.0154x over previous
//
#include <hip/hip_runtime.h>

#define H_  16
#define L_  1024
#define D_  1024
#define DH  64

typedef short bf16x8 __attribute__((ext_vector_type(8)));
typedef float f32x4  __attribute__((ext_vector_type(4)));

__device__ __forceinline__ ushort f2bf(float f) {
  union { float f; unsigned int u; } x; x.f = f;
  unsigned int u = x.u;
  u = (u + 0x7fffu + ((u >> 16) & 1u)) >> 16;   // RNE
  return (ushort)u;
}
__device__ __forceinline__ float bf2f(ushort s) {
  union { unsigned int u; float f; } x; x.u = ((unsigned int)s) << 16;
  return x.f;
}

// Software packed f32->bf16 (round-half-up) -> [bf16(b)<<16 | bf16(a)].
__device__ __forceinline__ unsigned int pkbf(float a, float b) {
  union { float f; unsigned int u; } xa, xb; xa.f = a; xb.f = b;
  unsigned int ua = xa.u + 0x8000u;
  unsigned int ub = xb.u + 0x8000u;
  return (ua >> 16) | (ub & 0xffff0000u);
}
__device__ __forceinline__ ushort lo16(unsigned int v) { return (ushort)v; }
__device__ __forceinline__ ushort hi16(unsigned int v) { return (ushort)(v >> 16); }

// QEr-region swizzle (ushort index): XOR bits[5:4] with bits[13:12]. Involution.
__device__ __forceinline__ int SZ(int F) { return F ^ (((F >> 12) & 3) << 4); }

// P-region swizzle: XOR addr bit4 (16-ushort granule; preserves 16B-aligned b128
// blocks) with row bit3. Store side key = (qd*4+r)>>3 = qd>>1; read side row = ln.
// Effect: P scalar stores qd-windows {0,16,0,16} -> {0,16,8,24} (2 lanes/bank, free);
// PV ds_read_b128 8-way -> 4-way.
__device__ __forceinline__ int PZ(int addr, int row) {
  return addr ^ (((row >> 3) & 1) << 4);
}

// Fragment-interleaved (AF) layout for an M x 1024 bf16 matrix.
__device__ __forceinline__ size_t afi(int m, int k) {
  return (((size_t)((m >> 7) * 32 + (k >> 5)) * 8 + ((m >> 4) & 7)) << 9)
       + ((size_t)((((k >> 3) & 3) << 4) + (m & 15)) << 3) + (k & 7);
}

// async global->LDS 16B per lane: dst = (wave-uniform) l + lane*16, src = per-lane g.
__device__ __forceinline__ void gl_lds16(const ushort* g, ushort* l) {
  __builtin_amdgcn_global_load_lds(
      (const __attribute__((address_space(1))) void*)g,
      (__attribute__((address_space(3))) void*)l, 16, 0, 0);
}

// Fused preprocessing: cvt3 (blocks 0..6143), wT4 (6144..7167), erF (7168..7199).
// All block-uniform branches; saves 2 kernel launches.
__global__ __launch_bounds__(256) void prep_kernel(
    const float* __restrict__ q, const float* __restrict__ k, const float* __restrict__ v,
    ushort* __restrict__ qb, ushort* __restrict__ kb, ushort* __restrict__ vb,
    const float* __restrict__ W0, const float* __restrict__ W1,
    const float* __restrict__ W2, const float* __restrict__ W3,
    ushort* __restrict__ T0, ushort* __restrict__ T1,
    ushort* __restrict__ T2, ushort* __restrict__ T3,
    const float* __restrict__ Er, ushort* __restrict__ ErF) {
  const int bx = blockIdx.x;
  const int tid = threadIdx.x;
  if (bx < 6144) {
    // ---- cvt3: q/k/v fp32 row-major -> bf16 AF layout
    const int z = bx >> 11;                 // /2048
    const int inner = bx & 2047;
    const float* in = (z == 0) ? q : (z == 1) ? k : v;
    ushort* out = (z == 0) ? qb : (z == 1) ? kb : vb;
    int idx = (inner * 256 + tid) * 8;
    int m = idx >> 10, kk = idx & 1023;
    float4 f0 = *(const float4*)(in + idx);
    float4 f1 = *(const float4*)(in + idx + 4);
    uint4 o;
    o.x = pkbf(f0.x, f0.y); o.y = pkbf(f0.z, f0.w);
    o.z = pkbf(f1.x, f1.y); o.w = pkbf(f1.z, f1.w);
    *(uint4*)(out + afi(m, kk)) = o;
  } else if (bx < 7168) {
    // ---- wT4: W fp32 [k][n] -> WT bf16 AF layout of BT[n][k]
    __shared__ ushort tt[64][72];
    const int b = bx - 6144;
    const int z = b >> 8;
    const int rem = b & 255;
    const int k0 = (rem >> 4) * 64, n0 = (rem & 15) * 64;
    const float* W = (z == 0) ? W0 : (z == 1) ? W1 : (z == 2) ? W2 : W3;
    ushort*     WT = (z == 0) ? T0 : (z == 1) ? T1 : (z == 2) ? T2 : T3;
    const int t = tid;
#pragma unroll
    for (int c = 0; c < 4; ++c) {
      int kk = c * 16 + (t >> 4);
      float4 f = *(const float4*)(W + (size_t)(k0 + kk) * 1024 + n0 + (t & 15) * 4);
      unsigned int p01 = pkbf(f.x, f.y), p23 = pkbf(f.z, f.w);
      tt[(t & 15) * 4 + 0][kk] = lo16(p01);
      tt[(t & 15) * 4 + 1][kk] = hi16(p01);
      tt[(t & 15) * 4 + 2][kk] = lo16(p23);
      tt[(t & 15) * 4 + 3][kk] = hi16(p23);
    }
    __syncthreads();
#pragma unroll
    for (int p = 0; p < 2; ++p) {
      int n = p * 32 + (t >> 3);
      *(uint4*)(WT + afi(n0 + n, k0 + (t & 7) * 8)) = *(const uint4*)(&tt[n][(t & 7) * 8]);
    }
  } else {
    // ---- erF: Er fp32 [1024][64] -> fragment-interleaved bf16
    int t = (bx - 7168) * 256 + tid;        // [0, 8192)
    int lane = t & 63, ph = (t >> 6) & 1, jg = t >> 7;
    int m = jg * 16 + (lane & 15);
    int kk = ph * 32 + (lane >> 4) * 8;
    float4 f0 = *(const float4*)(Er + m * 64 + kk);
    float4 f1 = *(const float4*)(Er + m * 64 + kk + 4);
    uint4 o;
    o.x = pkbf(f0.x, f0.y); o.y = pkbf(f0.z, f0.w);
    o.z = pkbf(f1.x, f1.y); o.w = pkbf(f1.z, f1.w);
    *(uint4*)(ErF + t * 8) = o;
  }
}

// Fused Q/K/V projection GEMM, m97-style: AF operands, global_load_lds staging.
__global__ __launch_bounds__(256) void gemm_qkv_kernel(
    const ushort* __restrict__ Aq, const ushort* __restrict__ Ak, const ushort* __restrict__ Av,
    const ushort* __restrict__ BTq, const ushort* __restrict__ BTk, const ushort* __restrict__ BTv,
    ushort* __restrict__ Cq, ushort* __restrict__ Ck, ushort* __restrict__ Cv) {
  __shared__ ushort lsA[4096];
  __shared__ ushort lsB[4096];
  const int z = blockIdx.z;
  const ushort* A  = (z == 0) ? Aq  : (z == 1) ? Ak  : Av;
  const ushort* BT = (z == 0) ? BTq : (z == 1) ? BTk : BTv;
  ushort*       Cp = (z == 0) ? Cq  : (z == 1) ? Ck  : Cv;

  const int tid  = threadIdx.x;
  const int w    = tid >> 6, lane = tid & 63, qd = lane >> 4, ln = lane & 15;
  const int rw   = w >> 1, cw = w & 1;
  const int mb   = blockIdx.y, nb = blockIdx.x;
  const int m0   = mb * 128, n0 = nb * 128;

  f32x4 acc[16];
#pragma unroll
  for (int i = 0; i < 16; ++i) acc[i] = (f32x4){0.f, 0.f, 0.f, 0.f};

  for (int kb = 0; kb < 32; ++kb) {
    const ushort* Ab = A  + ((size_t)(mb * 32 + kb) << 12);
    const ushort* Bb = BT + ((size_t)(nb * 32 + kb) << 12);
    const int c0 = 2 * w;
    gl_lds16(Ab + ((size_t)c0 << 9) + lane * 8,        lsA + (c0 << 9));
    gl_lds16(Ab + ((size_t)(c0 + 1) << 9) + lane * 8,  lsA + ((c0 + 1) << 9));
    gl_lds16(Bb + ((size_t)c0 << 9) + lane * 8,        lsB + (c0 << 9));
    gl_lds16(Bb + ((size_t)(c0 + 1) << 9) + lane * 8,  lsB + ((c0 + 1) << 9));
    __syncthreads();
    bf16x8 afr[4], bfr[4];
#pragma unroll
    for (int am = 0; am < 4; ++am)
      afr[am] = *(const bf16x8*)(lsA + ((rw * 4 + am) << 9) + lane * 8);
#pragma unroll
    for (int bn = 0; bn < 4; ++bn)
      bfr[bn] = *(const bf16x8*)(lsB + ((cw * 4 + bn) << 9) + lane * 8);
#pragma unroll
    for (int am = 0; am < 4; ++am)
#pragma unroll
      for (int bn = 0; bn < 4; ++bn)
        acc[am * 4 + bn] = __builtin_amdgcn_mfma_f32_16x16x32_bf16(afr[am], bfr[bn], acc[am * 4 + bn], 0, 0, 0);
    __syncthreads();
  }
#pragma unroll
  for (int am = 0; am < 4; ++am)
#pragma unroll
    for (int bn = 0; bn < 4; ++bn) {
      const int rbase = m0 + rw * 64 + am * 16 + qd * 4;
      const int colg  = n0 + cw * 64 + bn * 16 + ln;
      const unsigned int p01 = pkbf(acc[am * 4 + bn][0], acc[am * 4 + bn][1]);
      const unsigned int p23 = pkbf(acc[am * 4 + bn][2], acc[am * 4 + bn][3]);
      if (z == 0) {
        Cp[(size_t)(rbase + 0) * 1024 + colg] = lo16(p01);
        Cp[(size_t)(rbase + 1) * 1024 + colg] = hi16(p01);
        Cp[(size_t)(rbase + 2) * 1024 + colg] = lo16(p23);
        Cp[(size_t)(rbase + 3) * 1024 + colg] = hi16(p23);
      } else if (z == 1) {
        const int bh  = rbase >> 6;
        const int ki0 = rbase & 63;
        const int jg  = colg >> 4;
        const int ph  = ki0 >> 5;
        const int lanep = ((ki0 >> 3) & 3) * 16 + (colg & 15);
        const int jj0 = ki0 & 7;
        uint2 uu; uu.x = p01; uu.y = p23;
        *(uint2*)(Cp + (size_t)bh * 65536 + (size_t)((jg * 2 + ph) * 64 + lanep) * 8 + jj0) = uu;
      } else {
        const int bh = rbase >> 6;
        const int llow = colg >> 6, dd = colg & 63;
        const int g = dd >> 4, lnf = dd & 15;
        const ushort vals[4] = {lo16(p01), hi16(p01), lo16(p23), hi16(p23)};
#pragma unroll
        for (int r = 0; r < 4; ++r) {
          int l = ((rbase + r) & 63) * 16 + llow;
          int ks = l >> 5;
          int lanep = ((l >> 3) & 3) * 16 + lnf;
          int jj = l & 7;
          Cp[(size_t)bh * 65536 + (size_t)((g * 32 + ks) * 64 + lanep) * 8 + jj] = vals[r];
        }
      }
    }
}

// Merge GEMM, in-block split-K (8 waves), m97-style staging. A and BT in AF layout.
__global__ __launch_bounds__(512) void gemm_mg_kernel(const ushort* __restrict__ A,
                                                      const ushort* __restrict__ BT,
                                                      float* __restrict__ Cp) {
  __shared__ ushort lsA[2][4096];
  __shared__ ushort lsB[2][4096];
  __shared__ float  mgred[256 * 33];
  const int tid  = threadIdx.x;
  const int w    = tid >> 6, lane = tid & 63, qd = lane >> 4, ln = lane & 15;
  const int kh   = w >> 2, q = w & 3;
  const int rw   = q >> 1, cw = q & 1;
  const int mb   = blockIdx.y, nb = blockIdx.x;
  const int m0   = mb * 128, n0 = nb * 128;

  f32x4 acc[16];
#pragma unroll
  for (int i = 0; i < 16; ++i) acc[i] = (f32x4){0.f, 0.f, 0.f, 0.f};

  for (int kb = 0; kb < 16; ++kb) {
    const int kbi = kh * 16 + kb;
    const ushort* Ab = A  + ((size_t)(mb * 32 + kbi) << 12);
    const ushort* Bb = BT + ((size_t)(nb * 32 + kbi) << 12);
    const int c0 = 2 * q;
    gl_lds16(Ab + ((size_t)c0 << 9) + lane * 8,        lsA[kh] + (c0 << 9));
    gl_lds16(Ab + ((size_t)(c0 + 1) << 9) + lane * 8,  lsA[kh] + ((c0 + 1) << 9));
    gl_lds16(Bb + ((size_t)c0 << 9) + lane * 8,        lsB[kh] + (c0 << 9));
    gl_lds16(Bb + ((size_t)(c0 + 1) << 9) + lane * 8,  lsB[kh] + ((c0 + 1) << 9));
    __syncthreads();
    bf16x8 afr[4], bfr[4];
#pragma unroll
    for (int am = 0; am < 4; ++am)
      afr[am] = *(const bf16x8*)(lsA[kh] + ((rw * 4 + am) << 9) + lane * 8);
#pragma unroll
    for (int bn = 0; bn < 4; ++bn)
      bfr[bn] = *(const bf16x8*)(lsB[kh] + ((cw * 4 + bn) << 9) + lane * 8);
#pragma unroll
    for (int am = 0; am < 4; ++am)
#pragma unroll
      for (int bn = 0; bn < 4; ++bn)
        acc[am * 4 + bn] = __builtin_amdgcn_mfma_f32_16x16x32_bf16(afr[am], bfr[bn], acc[am * 4 + bn], 0, 0, 0);
    __syncthreads();
  }

  for (int half = 0; half < 2; ++half) {
    __syncthreads();
    if (w >= 4) {
      const int base = ((w - 4) * 64 + lane) * 33;
#pragma unroll
      for (int i = 0; i < 8; ++i)
#pragma unroll
        for (int c = 0; c < 4; ++c) mgred[base + i * 4 + c] = acc[half * 8 + i][c];
    }
    __syncthreads();
    if (w < 4) {
      const int base = (w * 64 + lane) * 33;
#pragma unroll
      for (int i = 0; i < 8; ++i)
#pragma unroll
        for (int c = 0; c < 4; ++c) acc[half * 8 + i][c] += mgred[base + i * 4 + c];
    }
  }
  if (w < 4) {
#pragma unroll
    for (int am = 0; am < 4; ++am)
#pragma unroll
      for (int bn = 0; bn < 4; ++bn) {
        const int rbase = m0 + rw * 64 + am * 16 + qd * 4;
        const int colg  = n0 + cw * 64 + bn * 16 + ln;
#pragma unroll
        for (int r = 0; r < 4; ++r)
          Cp[(size_t)(rbase + r) * 1024 + colg] = acc[am * 4 + bn][r];
      }
  }
}

// Fused relative attention — 16-row Q-tile + SZ swizzle (QEr epoch) + PZ swizzle
// (P epoch) + max-free softmax.
__global__ __launch_bounds__(512, 4) void attn_kernel(
    const ushort* __restrict__ QW, const ushort* __restrict__ KF,
    const ushort* __restrict__ VF, const ushort* __restrict__ ErF,
    ushort* __restrict__ Om) {
  __shared__ ushort qflat[17440];    // QEr rows 0..16 @ r*1025 (SZ); P rows @ r*1048 (PZ)
  __shared__ float  red[4][64][4];
  __shared__ float  stats[8][16];

  const int tid  = threadIdx.x;
  const int w    = tid >> 6;
  const int lane = tid & 63;
  const int qd   = lane >> 4;
  const int ln   = lane & 15;
  const int bh   = blockIdx.y;
  const int i0   = blockIdx.x << 4;
  const ushort* q  = QW + ((size_t)bh << 16);
  const ushort* kf = KF + ((size_t)bh << 16);
  const ushort* vf = VF + ((size_t)bh << 16);

  if (tid < 17) qflat[SZ(tid * 1025 + 1024)] = 0;   // the j==i+1 zeros

  bf16x8 a00 = *(const bf16x8*)(q + (size_t)(i0 + ln) * 64 + qd * 8);
  bf16x8 a01 = *(const bf16x8*)(q + (size_t)(i0 + ln) * 64 + 32 + qd * 8);
  const int row16 = (i0 + 16 > 1023) ? 1023 : i0 + 16;
  bf16x8 a10 = *(const bf16x8*)(q + (size_t)row16 * 64 + qd * 8);
  bf16x8 a11 = *(const bf16x8*)(q + (size_t)row16 * 64 + 32 + qd * 8);

  const int jg0 = w * 8;

  // ---- phase 0: QEr (stores via SZ)
#pragma unroll
  for (int f = 0; f < 8; ++f) {
    const int jg = jg0 + f;
    bf16x8 b0 = *(const bf16x8*)(ErF + (size_t)((jg * 2 + 0) * 64 + lane) * 8);
    bf16x8 b1 = *(const bf16x8*)(ErF + (size_t)((jg * 2 + 1) * 64 + lane) * 8);
    f32x4 acc = {0.f, 0.f, 0.f, 0.f};
    acc = __builtin_amdgcn_mfma_f32_16x16x32_bf16(a00, b0, acc, 0, 0, 0);
    acc = __builtin_amdgcn_mfma_f32_16x16x32_bf16(a01, b1, acc, 0, 0, 0);
    const int m = jg * 16 + ln;
    const unsigned int p01 = pkbf(acc[0], acc[1]);
    const unsigned int p23 = pkbf(acc[2], acc[3]);
    qflat[SZ((qd * 4 + 0) * 1025 + m)] = lo16(p01);
    qflat[SZ((qd * 4 + 1) * 1025 + m)] = hi16(p01);
    qflat[SZ((qd * 4 + 2) * 1025 + m)] = lo16(p23);
    qflat[SZ((qd * 4 + 3) * 1025 + m)] = hi16(p23);
    if (jg * 16 <= 1006 - i0) {
      f32x4 ac2 = {0.f, 0.f, 0.f, 0.f};
      ac2 = __builtin_amdgcn_mfma_f32_16x16x32_bf16(a10, b0, ac2, 0, 0, 0);
      ac2 = __builtin_amdgcn_mfma_f32_16x16x32_bf16(a11, b1, ac2, 0, 0, 0);
      if (qd == 0) qflat[SZ(16 * 1025 + m)] = f2bf(ac2[0]);
    }
  }

  // ---- phase 1: S = q @ kT
  f32x4 sfr[8];
#pragma unroll
  for (int f = 0; f < 8; ++f) {
    const int jg = jg0 + f;
    bf16x8 b0 = *(const bf16x8*)(kf + (size_t)((jg * 2 + 0) * 64 + lane) * 8);
    bf16x8 b1 = *(const bf16x8*)(kf + (size_t)((jg * 2 + 1) * 64 + lane) * 8);
    f32x4 acc = {0.f, 0.f, 0.f, 0.f};
    acc = __builtin_amdgcn_mfma_f32_16x16x32_bf16(a00, b0, acc, 0, 0, 0);
    acc = __builtin_amdgcn_mfma_f32_16x16x32_bf16(a01, b1, acc, 0, 0, 0);
    sfr[f] = acc;
  }
  __syncthreads();

  // ---- skew-add (branch-free flat gather through SZ)
#pragma unroll
  for (int f = 0; f < 8; ++f) {
    const int cj = 1023 - i0 + w * 128 + f * 16 + ln;
#pragma unroll
    for (int r = 0; r < 4; ++r)
      sfr[f][r] += bf2f(qflat[SZ((qd * 4 + r) * 1024 + cj)]);
  }
  __syncthreads();   // seal QEr epoch before P stores overwrite the region

  // ---- exp2 (no max subtraction), sums, P at stride 1048 via PZ
  const float cexp = 0.18033688011112042f;   // 0.125 * log2(e)
  const int pxk = ((qd >> 1) & 1) << 4;      // PZ key for rows qd*4+r (row>>3 = qd>>1)
  float vs[4] = {0.f, 0.f, 0.f, 0.f};
#pragma unroll
  for (int f = 0; f < 8; ++f) {
    const int j = w * 128 + f * 16 + ln;
    const float e0 = exp2f(sfr[f][0] * cexp);
    const float e1 = exp2f(sfr[f][1] * cexp);
    const float e2 = exp2f(sfr[f][2] * cexp);
    const float e3 = exp2f(sfr[f][3] * cexp);
    vs[0] += e0; vs[1] += e1; vs[2] += e2; vs[3] += e3;
    const unsigned int p01 = pkbf(e0, e1);
    const unsigned int p23 = pkbf(e2, e3);
    qflat[((qd * 4 + 0) * 1048 + j) ^ pxk] = lo16(p01);
    qflat[((qd * 4 + 1) * 1048 + j) ^ pxk] = hi16(p01);
    qflat[((qd * 4 + 2) * 1048 + j) ^ pxk] = lo16(p23);
    qflat[((qd * 4 + 3) * 1048 + j) ^ pxk] = hi16(p23);
  }
#pragma unroll
  for (int r = 0; r < 4; ++r) {
    float s = vs[r];
#pragma unroll
    for (int off = 1; off < 16; off <<= 1) s += __shfl_xor(s, off, 64);
    if (ln == 0) stats[w][qd * 4 + r] = s;
  }
  __syncthreads();
  float rrl[4];
#pragma unroll
  for (int r = 0; r < 4; ++r) {
    float s = 0.f;
#pragma unroll
    for (int ww = 0; ww < 8; ++ww) s += stats[ww][qd * 4 + r];
    rrl[r] = 1.0f / s;
  }

  // ---- phase 3: O = P @ v (split-K across wave pairs; 2 accumulate chains; PZ reads)
  const int g = w & 3, kh = w >> 2;
  f32x4 oacc0 = {0.f, 0.f, 0.f, 0.f};
  f32x4 oacc1 = {0.f, 0.f, 0.f, 0.f};
#pragma unroll
  for (int kc = 0; kc < 16; kc += 2) {
    const int ks0 = kh * 16 + kc;
    const int ks1 = ks0 + 1;
    bf16x8 ap0 = *(const bf16x8*)(qflat + PZ(ln * 1048 + ks0 * 32 + qd * 8, ln));
    bf16x8 bv0 = *(const bf16x8*)(vf + (size_t)((g * 32 + ks0) * 64 + lane) * 8);
    oacc0 = __builtin_amdgcn_mfma_f32_16x16x32_bf16(ap0, bv0, oacc0, 0, 0, 0);
    bf16x8 ap1 = *(const bf16x8*)(qflat + PZ(ln * 1048 + ks1 * 32 + qd * 8, ln));
    bf16x8 bv1 = *(const bf16x8*)(vf + (size_t)((g * 32 + ks1) * 64 + lane) * 8);
    oacc1 = __builtin_amdgcn_mfma_f32_16x16x32_bf16(ap1, bv1, oacc1, 0, 0, 0);
  }
  f32x4 oacc = oacc0 + oacc1;

  if (w >= 4) {
#pragma unroll
    for (int cc = 0; cc < 4; ++cc) red[w - 4][lane][cc] = oacc[cc];
  }
  __syncthreads();
  if (w < 4) {
    const int b = bh >> 4, h = bh & 15;
    // O in AF layout: m = b*1024 + i0 + qd*4 + r, kg = h*64 + g*16 + ln
    const int kg = h * 64 + g * 16 + ln;
    const int mbase = b * 1024 + i0;
    ushort* ob = Om + (((size_t)((mbase >> 7) * 32 + (kg >> 5)) * 8 + ((mbase >> 4) & 7)) << 9)
               + ((((kg >> 3) & 3) * 16 + qd * 4) << 3) + (kg & 7);
    const float o0 = (oacc[0] + red[w][lane][0]) * rrl[0];
    const float o1 = (oacc[1] + red[w][lane][1]) * rrl[1];
    const float o2 = (oacc[2] + red[w][lane][2]) * rrl[2];
    const float o3 = (oacc[3] + red[w][lane][3]) * rrl[3];
    const unsigned int p01 = pkbf(o0, o1);
    const unsigned int p23 = pkbf(o2, o3);
    ob[0]  = lo16(p01);
    ob[8]  = hi16(p01);
    ob[16] = lo16(p23);
    ob[24] = hi16(p23);
  }
}

extern "C" void kernel_launch(void* const* d_in, const int* in_sizes, int n_in,
                              void* d_out, int out_size, void* d_ws, size_t ws_size,
                              hipStream_t stream) {
  const float* query = (const float*)d_in[0];
  const float* key   = (const float*)d_in[1];
  const float* value = (const float*)d_in[2];
  const float* WQ    = (const float*)d_in[3];
  const float* WK    = (const float*)d_in[4];
  const float* WV    = (const float*)d_in[5];
  const float* Er    = (const float*)d_in[6];
  const float* WM    = (const float*)d_in[7];
  float* out = (float*)d_out;

  // workspace (ushort units): QW,KF,VF,O 4M each; ErF 64K; 4 WT 1M each; KB,VB 4M each.
  // QB (bf16 AF query) aliases O: consumed by qkv GEMM before attn writes O (AF).
  ushort* QW  = (ushort*)d_ws;
  ushort* KF  = QW  + (size_t)4096 * 1024;
  ushort* VF  = KF  + (size_t)4096 * 1024;
  ushort* O   = VF  + (size_t)4096 * 1024;
  ushort* ErF = O   + (size_t)4096 * 1024;
  ushort* WTQ = ErF + (size_t)65536;
  ushort* WTK = WTQ + (size_t)1024 * 1024;
  ushort* WTV = WTK + (size_t)1024 * 1024;
  ushort* WTM = WTV + (size_t)1024 * 1024;
  ushort* KB  = WTM + (size_t)1024 * 1024;
  ushort* VB  = KB  + (size_t)4096 * 1024;
  ushort* QB  = O;   // alias

  prep_kernel<<<7200, 256, 0, stream>>>(query, key, value, QB, KB, VB,
                                        WQ, WK, WV, WM, WTQ, WTK, WTV, WTM,
                                        Er, ErF);

  gemm_qkv_kernel<<<dim3(8, 32, 3), 256, 0, stream>>>(QB, KB, VB,
                                                      WTQ, WTK, WTV,
                                                      QW, KF, VF);

  attn_kernel<<<dim3(64, 64), 512, 0, stream>>>(QW, KF, VF, ErF, O);

  gemm_mg_kernel<<<dim3(8, 32), 512, 0, stream>>>(O, WTM, out);
}

// Round 7
// 263.560 us; speedup vs baseline: 1.0633x; 1.0237x over previous
//
#include <hip/hip_runtime.h>

#define H_  16
#define L_  1024
#define D_  1024
#define DH  64

typedef short bf16x8 __attribute__((ext_vector_type(8)));
typedef float f32x4  __attribute__((ext_vector_type(4)));

__device__ __forceinline__ ushort f2bf(float f) {
  union { float f; unsigned int u; } x; x.f = f;
  unsigned int u = x.u;
  u = (u + 0x7fffu + ((u >> 16) & 1u)) >> 16;   // RNE
  return (ushort)u;
}
__device__ __forceinline__ float bf2f(ushort s) {
  union { unsigned int u; float f; } x; x.u = ((unsigned int)s) << 16;
  return x.f;
}

// Software packed f32->bf16 (round-half-up) -> [bf16(b)<<16 | bf16(a)].
__device__ __forceinline__ unsigned int pkbf(float a, float b) {
  union { float f; unsigned int u; } xa, xb; xa.f = a; xb.f = b;
  unsigned int ua = xa.u + 0x8000u;
  unsigned int ub = xb.u + 0x8000u;
  return (ua >> 16) | (ub & 0xffff0000u);
}
__device__ __forceinline__ ushort lo16(unsigned int v) { return (ushort)v; }
__device__ __forceinline__ ushort hi16(unsigned int v) { return (ushort)(v >> 16); }

// QEr-region swizzle (ushort index): XOR bits[5:4] with bits[13:12]. Involution.
__device__ __forceinline__ int SZ(int F) { return F ^ (((F >> 12) & 3) << 4); }

// Fragment-interleaved (AF) layout for an M x 1024 bf16 matrix.
__device__ __forceinline__ size_t afi(int m, int k) {
  return (((size_t)((m >> 7) * 32 + (k >> 5)) * 8 + ((m >> 4) & 7)) << 9)
       + ((size_t)((((k >> 3) & 3) << 4) + (m & 15)) << 3) + (k & 7);
}

// async global->LDS 16B per lane: dst = (wave-uniform) l + lane*16, src = per-lane g.
__device__ __forceinline__ void gl_lds16(const ushort* g, ushort* l) {
  __builtin_amdgcn_global_load_lds(
      (const __attribute__((address_space(1))) void*)g,
      (__attribute__((address_space(3))) void*)l, 16, 0, 0);
}

// Fused preprocessing: cvt3 (blocks 0..6143), wT4 (6144..7167), erF (7168..7199).
// cvt3 is chunk-per-wave: each wave produces ONE 1KB AF chunk, lane l writes
// chunk+l*16B (contiguous 1KB wave store); reads cover full 128B lines per row.
__global__ __launch_bounds__(256) void prep_kernel(
    const float* __restrict__ q, const float* __restrict__ k, const float* __restrict__ v,
    ushort* __restrict__ qb, ushort* __restrict__ kb, ushort* __restrict__ vb,
    const float* __restrict__ W0, const float* __restrict__ W1,
    const float* __restrict__ W2, const float* __restrict__ W3,
    ushort* __restrict__ T0, ushort* __restrict__ T1,
    ushort* __restrict__ T2, ushort* __restrict__ T3,
    const float* __restrict__ Er, ushort* __restrict__ ErF) {
  const int bx = blockIdx.x;
  const int tid = threadIdx.x;
  if (bx < 6144) {
    // ---- cvt3: q/k/v fp32 row-major -> bf16 AF layout (chunk-per-wave)
    const int z = bx >> 11;                 // 2048 blocks per tensor
    const int inner = bx & 2047;
    const float* in = (z == 0) ? q : (z == 1) ? k : v;
    ushort* out = (z == 0) ? qb : (z == 1) ? kb : vb;
    const int wv = inner * 4 + (tid >> 6);  // chunk id, 0..8191
    const int l  = tid & 63;
    const int am = wv & 7, kb2 = (wv >> 3) & 31, mb = wv >> 8;
    const int m  = mb * 128 + am * 16 + (l & 15);
    const int kk = kb2 * 32 + (l >> 4) * 8;
    float4 f0 = *(const float4*)(in + (size_t)m * 1024 + kk);
    float4 f1 = *(const float4*)(in + (size_t)m * 1024 + kk + 4);
    uint4 o;
    o.x = pkbf(f0.x, f0.y); o.y = pkbf(f0.z, f0.w);
    o.z = pkbf(f1.x, f1.y); o.w = pkbf(f1.z, f1.w);
    *(uint4*)(out + ((size_t)wv << 9) + l * 8) = o;
  } else if (bx < 7168) {
    // ---- wT4: W fp32 [k][n] -> WT bf16 AF layout of BT[n][k]
    __shared__ ushort tt[64][72];
    const int b = bx - 6144;
    const int z = b >> 8;
    const int rem = b & 255;
    const int k0 = (rem >> 4) * 64, n0 = (rem & 15) * 64;
    const float* W = (z == 0) ? W0 : (z == 1) ? W1 : (z == 2) ? W2 : W3;
    ushort*     WT = (z == 0) ? T0 : (z == 1) ? T1 : (z == 2) ? T2 : T3;
    const int t = tid;
#pragma unroll
    for (int c = 0; c < 4; ++c) {
      int kk = c * 16 + (t >> 4);
      float4 f = *(const float4*)(W + (size_t)(k0 + kk) * 1024 + n0 + (t & 15) * 4);
      unsigned int p01 = pkbf(f.x, f.y), p23 = pkbf(f.z, f.w);
      tt[(t & 15) * 4 + 0][kk] = lo16(p01);
      tt[(t & 15) * 4 + 1][kk] = hi16(p01);
      tt[(t & 15) * 4 + 2][kk] = lo16(p23);
      tt[(t & 15) * 4 + 3][kk] = hi16(p23);
    }
    __syncthreads();
#pragma unroll
    for (int p = 0; p < 2; ++p) {
      int n = p * 32 + (t >> 3);
      *(uint4*)(WT + afi(n0 + n, k0 + (t & 7) * 8)) = *(const uint4*)(&tt[n][(t & 7) * 8]);
    }
  } else {
    // ---- erF: Er fp32 [1024][64] -> fragment-interleaved bf16
    int t = (bx - 7168) * 256 + tid;        // [0, 8192)
    int lane = t & 63, ph = (t >> 6) & 1, jg = t >> 7;
    int m = jg * 16 + (lane & 15);
    int kk = ph * 32 + (lane >> 4) * 8;
    float4 f0 = *(const float4*)(Er + m * 64 + kk);
    float4 f1 = *(const float4*)(Er + m * 64 + kk + 4);
    uint4 o;
    o.x = pkbf(f0.x, f0.y); o.y = pkbf(f0.z, f0.w);
    o.z = pkbf(f1.x, f1.y); o.w = pkbf(f1.z, f1.w);
    *(uint4*)(ErF + t * 8) = o;
  }
}

// Fused Q/K/V projection GEMM, m97-style: AF operands, global_load_lds staging.
__global__ __launch_bounds__(256) void gemm_qkv_kernel(
    const ushort* __restrict__ Aq, const ushort* __restrict__ Ak, const ushort* __restrict__ Av,
    const ushort* __restrict__ BTq, const ushort* __restrict__ BTk, const ushort* __restrict__ BTv,
    ushort* __restrict__ Cq, ushort* __restrict__ Ck, ushort* __restrict__ Cv) {
  __shared__ ushort lsA[4096];
  __shared__ ushort lsB[4096];
  const int z = blockIdx.z;
  const ushort* A  = (z == 0) ? Aq  : (z == 1) ? Ak  : Av;
  const ushort* BT = (z == 0) ? BTq : (z == 1) ? BTk : BTv;
  ushort*       Cp = (z == 0) ? Cq  : (z == 1) ? Ck  : Cv;

  const int tid  = threadIdx.x;
  const int w    = tid >> 6, lane = tid & 63, qd = lane >> 4, ln = lane & 15;
  const int rw   = w >> 1, cw = w & 1;
  const int mb   = blockIdx.y, nb = blockIdx.x;
  const int m0   = mb * 128, n0 = nb * 128;

  f32x4 acc[16];
#pragma unroll
  for (int i = 0; i < 16; ++i) acc[i] = (f32x4){0.f, 0.f, 0.f, 0.f};

  for (int kb = 0; kb < 32; ++kb) {
    const ushort* Ab = A  + ((size_t)(mb * 32 + kb) << 12);
    const ushort* Bb = BT + ((size_t)(nb * 32 + kb) << 12);
    const int c0 = 2 * w;
    gl_lds16(Ab + ((size_t)c0 << 9) + lane * 8,        lsA + (c0 << 9));
    gl_lds16(Ab + ((size_t)(c0 + 1) << 9) + lane * 8,  lsA + ((c0 + 1) << 9));
    gl_lds16(Bb + ((size_t)c0 << 9) + lane * 8,        lsB + (c0 << 9));
    gl_lds16(Bb + ((size_t)(c0 + 1) << 9) + lane * 8,  lsB + ((c0 + 1) << 9));
    __syncthreads();
    bf16x8 afr[4], bfr[4];
#pragma unroll
    for (int am = 0; am < 4; ++am)
      afr[am] = *(const bf16x8*)(lsA + ((rw * 4 + am) << 9) + lane * 8);
#pragma unroll
    for (int bn = 0; bn < 4; ++bn)
      bfr[bn] = *(const bf16x8*)(lsB + ((cw * 4 + bn) << 9) + lane * 8);
#pragma unroll
    for (int am = 0; am < 4; ++am)
#pragma unroll
      for (int bn = 0; bn < 4; ++bn)
        acc[am * 4 + bn] = __builtin_amdgcn_mfma_f32_16x16x32_bf16(afr[am], bfr[bn], acc[am * 4 + bn], 0, 0, 0);
    __syncthreads();
  }
#pragma unroll
  for (int am = 0; am < 4; ++am)
#pragma unroll
    for (int bn = 0; bn < 4; ++bn) {
      const int rbase = m0 + rw * 64 + am * 16 + qd * 4;
      const int colg  = n0 + cw * 64 + bn * 16 + ln;
      const unsigned int p01 = pkbf(acc[am * 4 + bn][0], acc[am * 4 + bn][1]);
      const unsigned int p23 = pkbf(acc[am * 4 + bn][2], acc[am * 4 + bn][3]);
      if (z == 0) {
        Cp[(size_t)(rbase + 0) * 1024 + colg] = lo16(p01);
        Cp[(size_t)(rbase + 1) * 1024 + colg] = hi16(p01);
        Cp[(size_t)(rbase + 2) * 1024 + colg] = lo16(p23);
        Cp[(size_t)(rbase + 3) * 1024 + colg] = hi16(p23);
      } else if (z == 1) {
        const int bh  = rbase >> 6;
        const int ki0 = rbase & 63;
        const int jg  = colg >> 4;
        const int ph  = ki0 >> 5;
        const int lanep = ((ki0 >> 3) & 3) * 16 + (colg & 15);
        const int jj0 = ki0 & 7;
        uint2 uu; uu.x = p01; uu.y = p23;
        *(uint2*)(Cp + (size_t)bh * 65536 + (size_t)((jg * 2 + ph) * 64 + lanep) * 8 + jj0) = uu;
      } else {
        const int bh = rbase >> 6;
        const int llow = colg >> 6, dd = colg & 63;
        const int g = dd >> 4, lnf = dd & 15;
        const ushort vals[4] = {lo16(p01), hi16(p01), lo16(p23), hi16(p23)};
#pragma unroll
        for (int r = 0; r < 4; ++r) {
          int l = ((rbase + r) & 63) * 16 + llow;
          int ks = l >> 5;
          int lanep = ((l >> 3) & 3) * 16 + lnf;
          int jj = l & 7;
          Cp[(size_t)bh * 65536 + (size_t)((g * 32 + ks) * 64 + lanep) * 8 + jj] = vals[r];
        }
      }
    }
}

// Merge GEMM, in-block split-K (8 waves), m97-style staging. A and BT in AF layout.
__global__ __launch_bounds__(512) void gemm_mg_kernel(const ushort* __restrict__ A,
                                                      const ushort* __restrict__ BT,
                                                      float* __restrict__ Cp) {
  __shared__ ushort lsA[2][4096];
  __shared__ ushort lsB[2][4096];
  __shared__ float  mgred[256 * 33];
  const int tid  = threadIdx.x;
  const int w    = tid >> 6, lane = tid & 63, qd = lane >> 4, ln = lane & 15;
  const int kh   = w >> 2, q = w & 3;
  const int rw   = q >> 1, cw = q & 1;
  const int mb   = blockIdx.y, nb = blockIdx.x;
  const int m0   = mb * 128, n0 = nb * 128;

  f32x4 acc[16];
#pragma unroll
  for (int i = 0; i < 16; ++i) acc[i] = (f32x4){0.f, 0.f, 0.f, 0.f};

  for (int kb = 0; kb < 16; ++kb) {
    const int kbi = kh * 16 + kb;
    const ushort* Ab = A  + ((size_t)(mb * 32 + kbi) << 12);
    const ushort* Bb = BT + ((size_t)(nb * 32 + kbi) << 12);
    const int c0 = 2 * q;
    gl_lds16(Ab + ((size_t)c0 << 9) + lane * 8,        lsA[kh] + (c0 << 9));
    gl_lds16(Ab + ((size_t)(c0 + 1) << 9) + lane * 8,  lsA[kh] + ((c0 + 1) << 9));
    gl_lds16(Bb + ((size_t)c0 << 9) + lane * 8,        lsB[kh] + (c0 << 9));
    gl_lds16(Bb + ((size_t)(c0 + 1) << 9) + lane * 8,  lsB[kh] + ((c0 + 1) << 9));
    __syncthreads();
    bf16x8 afr[4], bfr[4];
#pragma unroll
    for (int am = 0; am < 4; ++am)
      afr[am] = *(const bf16x8*)(lsA[kh] + ((rw * 4 + am) << 9) + lane * 8);
#pragma unroll
    for (int bn = 0; bn < 4; ++bn)
      bfr[bn] = *(const bf16x8*)(lsB[kh] + ((cw * 4 + bn) << 9) + lane * 8);
#pragma unroll
    for (int am = 0; am < 4; ++am)
#pragma unroll
      for (int bn = 0; bn < 4; ++bn)
        acc[am * 4 + bn] = __builtin_amdgcn_mfma_f32_16x16x32_bf16(afr[am], bfr[bn], acc[am * 4 + bn], 0, 0, 0);
    __syncthreads();
  }

  for (int half = 0; half < 2; ++half) {
    __syncthreads();
    if (w >= 4) {
      const int base = ((w - 4) * 64 + lane) * 33;
#pragma unroll
      for (int i = 0; i < 8; ++i)
#pragma unroll
        for (int c = 0; c < 4; ++c) mgred[base + i * 4 + c] = acc[half * 8 + i][c];
    }
    __syncthreads();
    if (w < 4) {
      const int base = (w * 64 + lane) * 33;
#pragma unroll
      for (int i = 0; i < 8; ++i)
#pragma unroll
        for (int c = 0; c < 4; ++c) acc[half * 8 + i][c] += mgred[base + i * 4 + c];
    }
  }
  if (w < 4) {
#pragma unroll
    for (int am = 0; am < 4; ++am)
#pragma unroll
      for (int bn = 0; bn < 4; ++bn) {
        const int rbase = m0 + rw * 64 + am * 16 + qd * 4;
        const int colg  = n0 + cw * 64 + bn * 16 + ln;
#pragma unroll
        for (int r = 0; r < 4; ++r)
          Cp[(size_t)(rbase + r) * 1024 + colg] = acc[am * 4 + bn][r];
      }
  }
}

// Fused relative attention — 16-row Q-tile + SZ swizzle (QEr epoch) + max-free softmax.
// P region back to identity addressing (R6's PZ swizzle measured WORSE: +1M conflicts,
// +6 VALUBusy — the b128 read start-banks are already uniform over multiples-of-4 and
// any 16B-granule XOR only permutes within that set).
__global__ __launch_bounds__(512, 4) void attn_kernel(
    const ushort* __restrict__ QW, const ushort* __restrict__ KF,
    const ushort* __restrict__ VF, const ushort* __restrict__ ErF,
    ushort* __restrict__ Om) {
  __shared__ ushort qflat[17440];    // QEr rows 0..16 @ r*1025 (SZ); P rows @ r*1048
  __shared__ float  red[4][64][4];
  __shared__ float  stats[8][16];

  const int tid  = threadIdx.x;
  const int w    = tid >> 6;
  const int lane = tid & 63;
  const int qd   = lane >> 4;
  const int ln   = lane & 15;
  const int bh   = blockIdx.y;
  const int i0   = blockIdx.x << 4;
  const ushort* q  = QW + ((size_t)bh << 16);
  const ushort* kf = KF + ((size_t)bh << 16);
  const ushort* vf = VF + ((size_t)bh << 16);

  if (tid < 17) qflat[SZ(tid * 1025 + 1024)] = 0;   // the j==i+1 zeros

  bf16x8 a00 = *(const bf16x8*)(q + (size_t)(i0 + ln) * 64 + qd * 8);
  bf16x8 a01 = *(const bf16x8*)(q + (size_t)(i0 + ln) * 64 + 32 + qd * 8);
  const int row16 = (i0 + 16 > 1023) ? 1023 : i0 + 16;
  bf16x8 a10 = *(const bf16x8*)(q + (size_t)row16 * 64 + qd * 8);
  bf16x8 a11 = *(const bf16x8*)(q + (size_t)row16 * 64 + 32 + qd * 8);

  const int jg0 = w * 8;

  // ---- phase 0: QEr (stores via SZ)
#pragma unroll
  for (int f = 0; f < 8; ++f) {
    const int jg = jg0 + f;
    bf16x8 b0 = *(const bf16x8*)(ErF + (size_t)((jg * 2 + 0) * 64 + lane) * 8);
    bf16x8 b1 = *(const bf16x8*)(ErF + (size_t)((jg * 2 + 1) * 64 + lane) * 8);
    f32x4 acc = {0.f, 0.f, 0.f, 0.f};
    acc = __builtin_amdgcn_mfma_f32_16x16x32_bf16(a00, b0, acc, 0, 0, 0);
    acc = __builtin_amdgcn_mfma_f32_16x16x32_bf16(a01, b1, acc, 0, 0, 0);
    const int m = jg * 16 + ln;
    const unsigned int p01 = pkbf(acc[0], acc[1]);
    const unsigned int p23 = pkbf(acc[2], acc[3]);
    qflat[SZ((qd * 4 + 0) * 1025 + m)] = lo16(p01);
    qflat[SZ((qd * 4 + 1) * 1025 + m)] = hi16(p01);
    qflat[SZ((qd * 4 + 2) * 1025 + m)] = lo16(p23);
    qflat[SZ((qd * 4 + 3) * 1025 + m)] = hi16(p23);
    if (jg * 16 <= 1006 - i0) {
      f32x4 ac2 = {0.f, 0.f, 0.f, 0.f};
      ac2 = __builtin_amdgcn_mfma_f32_16x16x32_bf16(a10, b0, ac2, 0, 0, 0);
      ac2 = __builtin_amdgcn_mfma_f32_16x16x32_bf16(a11, b1, ac2, 0, 0, 0);
      if (qd == 0) qflat[SZ(16 * 1025 + m)] = f2bf(ac2[0]);
    }
  }

  // ---- phase 1: S = q @ kT
  f32x4 sfr[8];
#pragma unroll
  for (int f = 0; f < 8; ++f) {
    const int jg = jg0 + f;
    bf16x8 b0 = *(const bf16x8*)(kf + (size_t)((jg * 2 + 0) * 64 + lane) * 8);
    bf16x8 b1 = *(const bf16x8*)(kf + (size_t)((jg * 2 + 1) * 64 + lane) * 8);
    f32x4 acc = {0.f, 0.f, 0.f, 0.f};
    acc = __builtin_amdgcn_mfma_f32_16x16x32_bf16(a00, b0, acc, 0, 0, 0);
    acc = __builtin_amdgcn_mfma_f32_16x16x32_bf16(a01, b1, acc, 0, 0, 0);
    sfr[f] = acc;
  }
  __syncthreads();

  // ---- skew-add (branch-free flat gather through SZ)
#pragma unroll
  for (int f = 0; f < 8; ++f) {
    const int cj = 1023 - i0 + w * 128 + f * 16 + ln;
#pragma unroll
    for (int r = 0; r < 4; ++r)
      sfr[f][r] += bf2f(qflat[SZ((qd * 4 + r) * 1024 + cj)]);
  }
  __syncthreads();   // seal QEr epoch before P stores overwrite the region

  // ---- exp2 (no max subtraction), sums, P at stride 1048
  const float cexp = 0.18033688011112042f;   // 0.125 * log2(e)
  float vs[4] = {0.f, 0.f, 0.f, 0.f};
#pragma unroll
  for (int f = 0; f < 8; ++f) {
    const int j = w * 128 + f * 16 + ln;
    const float e0 = exp2f(sfr[f][0] * cexp);
    const float e1 = exp2f(sfr[f][1] * cexp);
    const float e2 = exp2f(sfr[f][2] * cexp);
    const float e3 = exp2f(sfr[f][3] * cexp);
    vs[0] += e0; vs[1] += e1; vs[2] += e2; vs[3] += e3;
    const unsigned int p01 = pkbf(e0, e1);
    const unsigned int p23 = pkbf(e2, e3);
    qflat[(qd * 4 + 0) * 1048 + j] = lo16(p01);
    qflat[(qd * 4 + 1) * 1048 + j] = hi16(p01);
    qflat[(qd * 4 + 2) * 1048 + j] = lo16(p23);
    qflat[(qd * 4 + 3) * 1048 + j] = hi16(p23);
  }
#pragma unroll
  for (int r = 0; r < 4; ++r) {
    float s = vs[r];
#pragma unroll
    for (int off = 1; off < 16; off <<= 1) s += __shfl_xor(s, off, 64);
    if (ln == 0) stats[w][qd * 4 + r] = s;
  }
  __syncthreads();
  float rrl[4];
#pragma unroll
  for (int r = 0; r < 4; ++r) {
    float s = 0.f;
#pragma unroll
    for (int ww = 0; ww < 8; ++ww) s += stats[ww][qd * 4 + r];
    rrl[r] = 1.0f / s;
  }

  // ---- phase 3: O = P @ v (split-K across wave pairs; 2 accumulate chains)
  const int g = w & 3, kh = w >> 2;
  f32x4 oacc0 = {0.f, 0.f, 0.f, 0.f};
  f32x4 oacc1 = {0.f, 0.f, 0.f, 0.f};
#pragma unroll
  for (int kc = 0; kc < 16; kc += 2) {
    const int ks0 = kh * 16 + kc;
    const int ks1 = ks0 + 1;
    bf16x8 ap0 = *(const bf16x8*)(qflat + ln * 1048 + ks0 * 32 + qd * 8);
    bf16x8 bv0 = *(const bf16x8*)(vf + (size_t)((g * 32 + ks0) * 64 + lane) * 8);
    oacc0 = __builtin_amdgcn_mfma_f32_16x16x32_bf16(ap0, bv0, oacc0, 0, 0, 0);
    bf16x8 ap1 = *(const bf16x8*)(qflat + ln * 1048 + ks1 * 32 + qd * 8);
    bf16x8 bv1 = *(const bf16x8*)(vf + (size_t)((g * 32 + ks1) * 64 + lane) * 8);
    oacc1 = __builtin_amdgcn_mfma_f32_16x16x32_bf16(ap1, bv1, oacc1, 0, 0, 0);
  }
  f32x4 oacc = oacc0 + oacc1;

  if (w >= 4) {
#pragma unroll
    for (int cc = 0; cc < 4; ++cc) red[w - 4][lane][cc] = oacc[cc];
  }
  __syncthreads();
  if (w < 4) {
    const int b = bh >> 4, h = bh & 15;
    // O in AF layout: m = b*1024 + i0 + qd*4 + r, kg = h*64 + g*16 + ln
    const int kg = h * 64 + g * 16 + ln;
    const int mbase = b * 1024 + i0;
    ushort* ob = Om + (((size_t)((mbase >> 7) * 32 + (kg >> 5)) * 8 + ((mbase >> 4) & 7)) << 9)
               + ((((kg >> 3) & 3) * 16 + qd * 4) << 3) + (kg & 7);
    const float o0 = (oacc[0] + red[w][lane][0]) * rrl[0];
    const float o1 = (oacc[1] + red[w][lane][1]) * rrl[1];
    const float o2 = (oacc[2] + red[w][lane][2]) * rrl[2];
    const float o3 = (oacc[3] + red[w][lane][3]) * rrl[3];
    const unsigned int p01 = pkbf(o0, o1);
    const unsigned int p23 = pkbf(o2, o3);
    ob[0]  = lo16(p01);
    ob[8]  = hi16(p01);
    ob[16] = lo16(p23);
    ob[24] = hi16(p23);
  }
}

extern "C" void kernel_launch(void* const* d_in, const int* in_sizes, int n_in,
                              void* d_out, int out_size, void* d_ws, size_t ws_size,
                              hipStream_t stream) {
  const float* query = (const float*)d_in[0];
  const float* key   = (const float*)d_in[1];
  const float* value = (const float*)d_in[2];
  const float* WQ    = (const float*)d_in[3];
  const float* WK    = (const float*)d_in[4];
  const float* WV    = (const float*)d_in[5];
  const float* Er    = (const float*)d_in[6];
  const float* WM    = (const float*)d_in[7];
  float* out = (float*)d_out;

  // workspace (ushort units): QW,KF,VF,O 4M each; ErF 64K; 4 WT 1M each; KB,VB 4M each.
  // QB (bf16 AF query) aliases O: consumed by qkv GEMM before attn writes O (AF).
  ushort* QW  = (ushort*)d_ws;
  ushort* KF  = QW  + (size_t)4096 * 1024;
  ushort* VF  = KF  + (size_t)4096 * 1024;
  ushort* O   = VF  + (size_t)4096 * 1024;
  ushort* ErF = O   + (size_t)4096 * 1024;
  ushort* WTQ = ErF + (size_t)65536;
  ushort* WTK = WTQ + (size_t)1024 * 1024;
  ushort* WTV = WTK + (size_t)1024 * 1024;
  ushort* WTM = WTV + (size_t)1024 * 1024;
  ushort* KB  = WTM + (size_t)1024 * 1024;
  ushort* VB  = KB  + (size_t)4096 * 1024;
  ushort* QB  = O;   // alias

  prep_kernel<<<7200, 256, 0, stream>>>(query, key, value, QB, KB, VB,
                                        WQ, WK, WV, WM, WTQ, WTK, WTV, WTM,
                                        Er, ErF);

  gemm_qkv_kernel<<<dim3(8, 32, 3), 256, 0, stream>>>(QB, KB, VB,
                                                      WTQ, WTK, WTV,
                                                      QW, KF, VF);

  attn_kernel<<<dim3(64, 64), 512, 0, stream>>>(QW, KF, VF, ErF, O);

  gemm_mg_kernel<<<dim3(8, 32), 512, 0, stream>>>(O, WTM, out);
}